// Round 13
// baseline (405.375 us; speedup 1.0000x reference)
//
#include <hip/hip_runtime.h>
#include <hip/hip_bf16.h>
#include <math.h>

typedef __hip_bfloat16 bf16;
typedef __bf16 bf16x8 __attribute__((ext_vector_type(8)));
typedef float floatx4 __attribute__((ext_vector_type(4)));

__device__ __forceinline__ unsigned short f2bu(float f) {
    bf16 b = __float2bfloat16(f);
    return __builtin_bit_cast(unsigned short, b);
}
__device__ __forceinline__ float bu2f(unsigned short u) {
    return __uint_as_float(((unsigned)u) << 16);
}

// ====== MFMA GEMM + fused alpha: C[N,16H] = X[N,128] @ W[128,16H] ===========
// K=128 in LDS, one staging phase. Fragment layouts (m89/m91-verified):
// A[m=lane&15][k=quad*8+j], B[k=quad*8+j][n=lane&15], D[row=quad*4+reg][col=lane&15].
template<typename XT, int H>
__global__ __launch_bounds__(256) void gemm_mfma(
    const XT* __restrict__ X, const float* __restrict__ W,
    const float* __restrict__ a_src, const float* __restrict__ a_dst,
    bf16* __restrict__ Hout, float* __restrict__ asrc, float* __restrict__ adst,
    int N)
{
    constexpr int M = H * 16;
    constexpr int KP = 136;              // padded k-stride (bf16 elems)
    constexpr int NT = M / 16;           // 16-col tiles per wave
    constexpr int HPQ = H / 4;           // heads per quarter-thread
    __shared__ __align__(16) unsigned short Wt[M * KP];   // W^T: [n][k]
    __shared__ __align__(16) unsigned short As[64 * KP];  // A: [m][k]; reused for D
    __shared__ float As_s[M], Ad_s[M];
    int tid = threadIdx.x;
    int r0 = blockIdx.x * 64;

    for (int i = tid; i < M; i += 256) { As_s[i] = a_src[i]; Ad_s[i] = a_dst[i]; }
    for (int idx = tid; idx < 128 * M; idx += 256) {
        int k = idx / M, m = idx % M;
        Wt[m * KP + k] = f2bu(W[idx]);
    }
    if constexpr (__is_same(XT, float)) {
        for (int idx = tid; idx < 64 * 32; idx += 256) {
            int row = idx >> 5, c4 = (idx & 31) * 4;
            int grow = r0 + row;
            float4 v = make_float4(0.f, 0.f, 0.f, 0.f);
            if (grow < N)
                v = *reinterpret_cast<const float4*>(X + (size_t)grow * 128 + c4);
            unsigned short* a = &As[row * KP + c4];
            a[0] = f2bu(v.x); a[1] = f2bu(v.y); a[2] = f2bu(v.z); a[3] = f2bu(v.w);
        }
    } else {
        for (int idx = tid; idx < 64 * 16; idx += 256) {
            int row = idx >> 4, c8 = (idx & 15) * 8;
            int grow = r0 + row;
            uint4 v = make_uint4(0u, 0u, 0u, 0u);
            if (grow < N)
                v = *reinterpret_cast<const uint4*>((const unsigned short*)X + (size_t)grow * 128 + c8);
            *reinterpret_cast<uint4*>(&As[row * KP + c8]) = v;
        }
    }
    __syncthreads();

    int w = tid >> 6, l = tid & 63, q = l >> 4, c = l & 15;
    floatx4 acc[NT];
    #pragma unroll
    for (int t = 0; t < NT; ++t) acc[t] = (floatx4){0.f, 0.f, 0.f, 0.f};

    #pragma unroll
    for (int kc = 0; kc < 4; ++kc) {
        bf16x8 a = *reinterpret_cast<const bf16x8*>(&As[(w * 16 + c) * KP + kc * 32 + q * 8]);
        #pragma unroll
        for (int t = 0; t < NT; ++t) {
            bf16x8 b = *reinterpret_cast<const bf16x8*>(&Wt[(t * 16 + c) * KP + kc * 32 + q * 8]);
            acc[t] = __builtin_amdgcn_mfma_f32_16x16x32_bf16(a, b, acc[t], 0, 0, 0);
        }
    }
    __syncthreads();
    #pragma unroll
    for (int t = 0; t < NT; ++t)
        #pragma unroll
        for (int r = 0; r < 4; ++r)
            As[(w * 16 + q * 4 + r) * KP + t * 16 + c] = f2bu(acc[t][r]);
    __syncthreads();
    for (int idx = tid; idx < 64 * (M / 8); idx += 256) {
        int row = idx / (M / 8), g = idx % (M / 8);
        int grow = r0 + row;
        if (grow < N)
            *reinterpret_cast<uint4*>(Hout + (size_t)grow * M + g * 8) =
                *reinterpret_cast<const uint4*>(&As[row * KP + g * 8]);
    }
    {
        int r = tid >> 2, qq = tid & 3;
        int grow = r0 + r;
        if (grow < N) {
            #pragma unroll
            for (int hh = 0; hh < HPQ; ++hh) {
                int hd = qq * HPQ + hh;
                float s1 = 0.f, s2 = 0.f;
                #pragma unroll
                for (int f = 0; f < 16; f += 2) {
                    unsigned u = *reinterpret_cast<const unsigned*>(&As[r * KP + hd * 16 + f]);
                    float v0 = __uint_as_float(u << 16);
                    float v1 = __uint_as_float(u & 0xffff0000u);
                    s1 += v0 * As_s[hd * 16 + f] + v1 * As_s[hd * 16 + f + 1];
                    s2 += v0 * Ad_s[hd * 16 + f] + v1 * Ad_s[hd * 16 + f + 1];
                }
                asrc[(size_t)grow * H + hd] = s1;
                adst[(size_t)grow * H + hd] = s2;
            }
        }
    }
}

// ============== atomic-free CSR build: counting sort by dst ==================
// Fixed per-bucket regions of CSR_REG slots (24-sigma over mean bucket load)
// remove the cross-bucket prefix entirely. pairs/col are gapped; per-dst
// extents published as int2 ptrSE[d] = (start, end).
#define CSR_CH  4096
#define CSR_REG 8192

__global__ __launch_bounds__(256) void csr_hist(
    const int* __restrict__ ei, int E, int DPB, int* __restrict__ histM)
{
    __shared__ int cnt[256];
    int tid = threadIdx.x;
    cnt[tid] = 0;
    __syncthreads();
    int e0 = blockIdx.x * CSR_CH;
    int e1 = min(E, e0 + CSR_CH);
    for (int e = e0 + tid; e < e1; e += 256)
        atomicAdd(&cnt[ei[E + e] / DPB], 1);
    __syncthreads();
    histM[blockIdx.x * 256 + tid] = cnt[tid];
}

// per-bucket exclusive scan over chunk counts -> absolute cursors (b*REG base)
__global__ __launch_bounds__(256) void csr_colscan(
    const int* __restrict__ histM, int NBLK,
    int* __restrict__ offT, int* __restrict__ btot)
{
    __shared__ int sm[512];
    int b = blockIdx.x;
    int tid = threadIdx.x;
    int i0 = tid, i1 = tid + 256;
    sm[i0] = (i0 < NBLK) ? histM[i0 * 256 + b] : 0;
    sm[i1] = (i1 < NBLK) ? histM[i1 * 256 + b] : 0;
    __syncthreads();
    #pragma unroll
    for (int o = 1; o < 512; o <<= 1) {
        int t0 = (i0 >= o) ? sm[i0 - o] : 0;
        int t1 = (i1 >= o) ? sm[i1 - o] : 0;
        __syncthreads();
        sm[i0] += t0; sm[i1] += t1;
        __syncthreads();
    }
    if (i0 < NBLK) offT[b * NBLK + i0] = b * CSR_REG + ((i0 == 0) ? 0 : sm[i0 - 1]);
    if (i1 < NBLK) offT[b * NBLK + i1] = b * CSR_REG + sm[i1 - 1];
    if (tid == 0) btot[b] = sm[511];
}

__global__ __launch_bounds__(256) void csr_pair_scatter(
    const int* __restrict__ ei, int E, int DPB,
    const int* __restrict__ offT, int NBLK,
    unsigned* __restrict__ pairs)
{
    __shared__ int cnt[256];
    int tid = threadIdx.x;
    int blk = blockIdx.x;
    cnt[tid] = offT[tid * NBLK + blk];
    __syncthreads();
    int e0 = blk * CSR_CH;
    int e1 = min(E, e0 + CSR_CH);
    for (int e = e0 + tid; e < e1; e += 256) {
        int s = ei[e];
        int d = ei[E + e];
        int b = d / DPB;
        int dloc = d - b * DPB;
        int pos = atomicAdd(&cnt[b], 1);
        pairs[pos] = ((unsigned)dloc << 17) | (unsigned)s;
    }
}

__global__ __launch_bounds__(256) void csr_fine(
    const unsigned* __restrict__ pairs, const int* __restrict__ btot,
    int DPB, int N, int2* __restrict__ ptrSE, int* __restrict__ col)
{
    __shared__ int sm[512];
    __shared__ int off[512];
    int b = blockIdx.x;
    int tid = threadIdx.x;
    int base = b * CSR_REG;
    int tot = btot[b];
    int d0 = b * DPB;
    int i0 = tid, i1 = tid + 256;
    sm[i0] = 0; sm[i1] = 0;
    __syncthreads();
    for (int i = tid; i < tot; i += 256)
        atomicAdd(&sm[pairs[base + i] >> 17], 1);
    __syncthreads();
    #pragma unroll
    for (int o = 1; o < 512; o <<= 1) {
        int t0 = (i0 >= o) ? sm[i0 - o] : 0;
        int t1 = (i1 >= o) ? sm[i1 - o] : 0;
        __syncthreads();
        sm[i0] += t0; sm[i1] += t1;
        __syncthreads();
    }
    int s0e = base + ((i0 == 0) ? 0 : sm[i0 - 1]);
    int s1e = base + sm[i1 - 1];
    off[i0] = s0e;
    off[i1] = s1e;
    if (i0 < DPB && d0 + i0 < N) ptrSE[d0 + i0] = make_int2(s0e, base + sm[i0]);
    if (i1 < DPB && d0 + i1 < N) ptrSE[d0 + i1] = make_int2(s1e, base + sm[i1]);
    __syncthreads();
    for (int i = tid; i < tot; i += 256) {
        unsigned p = pairs[base + i];
        int pos = atomicAdd(&off[p >> 17], 1);
        col[pos] = (int)(p & 0x1FFFFu);
    }
}

// ------- CSR agg + bias + LN + ELU fused: LPD-lane subgroup per dst ---------
// PF = M/LPD = 2 (one dword per lane per edge). L1: LPD=64 (1 dst/wave);
// L2: LPD=32 (2 dsts/wave -> 2x in-flight gathers). col read as aligned int4.
template<int H, int F, int LPD>
__global__ __launch_bounds__(64) void agg_ln_kernel(
    const int2* __restrict__ ptrSE, const int* __restrict__ col,
    const float* __restrict__ asrc, const float* __restrict__ adst,
    const bf16* __restrict__ hb, const float* __restrict__ bias,
    const float* __restrict__ g, const float* __restrict__ be,
    bf16* __restrict__ out, int N)
{
    constexpr int M = H * F;
    constexpr int PF = M / LPD;
    static_assert(PF == 2, "PF must be 2");
    constexpr int DPW = 64 / LPD;
    int sub = threadIdx.x / LPD;
    int j = threadIdx.x % LPD;
    int d = blockIdx.x * DPW + sub;
    if (d >= N) return;
    int f0 = j * 2;
    int hd = f0 / F;
    int2 se = ptrSE[d];
    int e = se.x, end = se.y;
    float adst_h = adst[d * H + hd];
    const unsigned* hw = (const unsigned*)hb;   // dword view; feature pair f0/2

    float a00, a01, a10 = 0.f, a11 = 0.f, a20 = 0.f, a21 = 0.f, a30 = 0.f, a31 = 0.f;
    float dn0, dn1 = 0.f, dn2 = 0.f, dn3 = 0.f;

    { // self loop -> chain 0
        float lg = asrc[d * H + hd] + adst_h;
        lg = lg > 0.f ? lg : 0.2f * lg;
        float w = __expf(lg);
        unsigned u = hw[(size_t)d * (M / 2) + j];
        a00 = w * __uint_as_float(u << 16);
        a01 = w * __uint_as_float(u & 0xffff0000u);
        dn0 = w;
    }

    // peel to 16B alignment of col
    for (; e < end && (e & 3); ++e) {
        int s = col[e];
        float lg = asrc[s * H + hd] + adst_h;
        lg = lg > 0.f ? lg : 0.2f * lg;
        float w = __expf(lg);
        unsigned u = hw[(size_t)s * (M / 2) + j];
        a00 += w * __uint_as_float(u << 16);
        a01 += w * __uint_as_float(u & 0xffff0000u);
        dn0 += w;
    }
    for (; e + 4 <= end; e += 4) {
        int4 c4 = *reinterpret_cast<const int4*>(&col[e]);
        float l0 = asrc[c4.x * H + hd];
        float l1 = asrc[c4.y * H + hd];
        float l2 = asrc[c4.z * H + hd];
        float l3 = asrc[c4.w * H + hd];
        unsigned u0 = hw[(size_t)c4.x * (M / 2) + j];
        unsigned u1 = hw[(size_t)c4.y * (M / 2) + j];
        unsigned u2 = hw[(size_t)c4.z * (M / 2) + j];
        unsigned u3 = hw[(size_t)c4.w * (M / 2) + j];
        l0 += adst_h; l0 = l0 > 0.f ? l0 : 0.2f * l0; float w0 = __expf(l0);
        l1 += adst_h; l1 = l1 > 0.f ? l1 : 0.2f * l1; float w1 = __expf(l1);
        l2 += adst_h; l2 = l2 > 0.f ? l2 : 0.2f * l2; float w2 = __expf(l2);
        l3 += adst_h; l3 = l3 > 0.f ? l3 : 0.2f * l3; float w3 = __expf(l3);
        a00 += w0 * __uint_as_float(u0 << 16);
        a01 += w0 * __uint_as_float(u0 & 0xffff0000u);
        a10 += w1 * __uint_as_float(u1 << 16);
        a11 += w1 * __uint_as_float(u1 & 0xffff0000u);
        a20 += w2 * __uint_as_float(u2 << 16);
        a21 += w2 * __uint_as_float(u2 & 0xffff0000u);
        a30 += w3 * __uint_as_float(u3 << 16);
        a31 += w3 * __uint_as_float(u3 & 0xffff0000u);
        dn0 += w0; dn1 += w1; dn2 += w2; dn3 += w3;
    }
    for (; e < end; ++e) {
        int s = col[e];
        float lg = asrc[s * H + hd] + adst_h;
        lg = lg > 0.f ? lg : 0.2f * lg;
        float w = __expf(lg);
        unsigned u = hw[(size_t)s * (M / 2) + j];
        a00 += w * __uint_as_float(u << 16);
        a01 += w * __uint_as_float(u & 0xffff0000u);
        dn0 += w;
    }

    float den = dn0 + dn1 + dn2 + dn3;
    float rden = 1.f / (den + 1e-16f);
    float o0 = (a00 + a10 + a20 + a30) * rden + bias[f0];
    float o1 = (a01 + a11 + a21 + a31) * rden + bias[f0 + 1];
    float sm1 = o0 + o1, sm2 = o0 * o0 + o1 * o1;
    #pragma unroll
    for (int off = LPD / 2; off >= 1; off >>= 1) {
        sm1 += __shfl_xor(sm1, off, LPD);
        sm2 += __shfl_xor(sm2, off, LPD);
    }
    float mu = sm1 * (1.f / M);
    float var = sm2 * (1.f / M) - mu * mu;
    float inv = rsqrtf(var + 1e-5f);
    float y0 = (o0 - mu) * inv * g[f0] + be[f0];
    float y1 = (o1 - mu) * inv * g[f0 + 1] + be[f0 + 1];
    y0 = y0 > 0.f ? y0 : expm1f(y0);
    y1 = y1 > 0.f ? y1 : expm1f(y1);
    unsigned u = (unsigned)f2bu(y0) | ((unsigned)f2bu(y1) << 16);
    *reinterpret_cast<unsigned*>((unsigned short*)out + (size_t)d * M + f0) = u;
}

// ------- layer 3 GEMM (64->10) + alpha fused: one thread per node -----------
__global__ __launch_bounds__(256) void gemm3_alpha(
    const bf16* __restrict__ X, const float* __restrict__ W3,
    const float* __restrict__ av_src, const float* __restrict__ av_dst,
    bf16* __restrict__ h3, float* __restrict__ asrc, float* __restrict__ adst,
    int N)
{
    __shared__ float Wl[640];
    int tid = threadIdx.x;
    for (int i = tid; i < 640; i += 256) Wl[i] = W3[i];
    __syncthreads();
    int n = blockIdx.x * 256 + tid;
    if (n >= N) return;
    float h[10];
    #pragma unroll
    for (int j = 0; j < 10; ++j) h[j] = 0.f;
    const unsigned short* xr = (const unsigned short*)X + (size_t)n * 64;
    for (int k2 = 0; k2 < 32; ++k2) {
        unsigned u = *reinterpret_cast<const unsigned*>(xr + k2 * 2);
        float x0 = __uint_as_float(u << 16);
        float x1 = __uint_as_float(u & 0xffff0000u);
        #pragma unroll
        for (int j = 0; j < 10; ++j)
            h[j] += x0 * Wl[(k2 * 2) * 10 + j] + x1 * Wl[(k2 * 2 + 1) * 10 + j];
    }
    float s1 = 0.f, s2 = 0.f;
    unsigned short* hr = (unsigned short*)h3 + (size_t)n * 16;
    #pragma unroll
    for (int j = 0; j < 10; j += 2) {
        unsigned u = (unsigned)f2bu(h[j]) | ((unsigned)f2bu(h[j + 1]) << 16);
        *reinterpret_cast<unsigned*>(hr + j) = u;
    }
    #pragma unroll
    for (int j = 0; j < 10; ++j) {
        s1 += h[j] * av_src[j];
        s2 += h[j] * av_dst[j];
    }
    asrc[n] = s1;
    adst[n] = s2;
}

// --- layer-3 agg + bias + log_softmax fused: 16-lane subgroup per dst -------
__global__ __launch_bounds__(256) void agg_l3_final(
    const int2* __restrict__ ptrSE, const int* __restrict__ col,
    const float* __restrict__ asrc, const float* __restrict__ adst,
    const bf16* __restrict__ h, const float* __restrict__ b3,
    float* __restrict__ out, int N)
{
    int tid = threadIdx.x;
    int sub16 = tid >> 4;
    int j = tid & 15;
    int d = blockIdx.x * 16 + sub16;
    if (d >= N) return;
    const unsigned short* hu = (const unsigned short*)h;
    int2 se = ptrSE[d];
    int e = se.x, end = se.y;
    float adst_d = adst[d];
    float lg = asrc[d] + adst_d;
    lg = lg > 0.f ? lg : 0.2f * lg;
    float w = __expf(lg);
    bool act = j < 10;
    float a0 = act ? w * bu2f(hu[(size_t)d * 16 + j]) : 0.f;
    float a1 = 0.f, a2 = 0.f, a3 = 0.f;
    float d0 = w, d1 = 0.f, d2 = 0.f, d3 = 0.f;
    for (; e + 4 <= end; e += 4) {
        int s0 = col[e + 0], s1 = col[e + 1], s2 = col[e + 2], s3 = col[e + 3];
        float l0 = asrc[s0], l1 = asrc[s1], l2 = asrc[s2], l3 = asrc[s3];
        float v0 = act ? bu2f(hu[(size_t)s0 * 16 + j]) : 0.f;
        float v1 = act ? bu2f(hu[(size_t)s1 * 16 + j]) : 0.f;
        float v2 = act ? bu2f(hu[(size_t)s2 * 16 + j]) : 0.f;
        float v3 = act ? bu2f(hu[(size_t)s3 * 16 + j]) : 0.f;
        l0 += adst_d; l0 = l0 > 0.f ? l0 : 0.2f * l0; float w0 = __expf(l0);
        l1 += adst_d; l1 = l1 > 0.f ? l1 : 0.2f * l1; float w1 = __expf(l1);
        l2 += adst_d; l2 = l2 > 0.f ? l2 : 0.2f * l2; float w2 = __expf(l2);
        l3 += adst_d; l3 = l3 > 0.f ? l3 : 0.2f * l3; float w3 = __expf(l3);
        a0 += w0 * v0; a1 += w1 * v1; a2 += w2 * v2; a3 += w3 * v3;
        d0 += w0; d1 += w1; d2 += w2; d3 += w3;
    }
    for (; e < end; ++e) {
        int s = col[e];
        float l = asrc[s] + adst_d;
        l = l > 0.f ? l : 0.2f * l;
        float ww = __expf(l);
        if (act) a0 += ww * bu2f(hu[(size_t)s * 16 + j]);
        d0 += ww;
    }
    float den = d0 + d1 + d2 + d3;
    float v = (a0 + a1 + a2 + a3) / (den + 1e-16f);
    float lv = act ? v + b3[j] : -1e30f;
    float mx = lv;
    #pragma unroll
    for (int off = 1; off < 16; off <<= 1) mx = fmaxf(mx, __shfl_xor(mx, off, 16));
    float ev = act ? __expf(lv - mx) : 0.f;
    float se2 = ev;
    #pragma unroll
    for (int off = 1; off < 16; off <<= 1) se2 += __shfl_xor(se2, off, 16);
    float ls = mx + logf(se2);
    if (act) out[(size_t)d * 10 + j] = lv - ls;
}

static inline int cdiv(long a, long b) { return (int)((a + b - 1) / b); }

extern "C" void kernel_launch(void* const* d_in, const int* in_sizes, int n_in,
                              void* d_out, int out_size, void* d_ws, size_t ws_size,
                              hipStream_t stream)
{
    const float* x   = (const float*)d_in[0];
    const int*   ei  = (const int*)d_in[1];
    const float* W1  = (const float*)d_in[2];
    const float* as1 = (const float*)d_in[3];
    const float* ad1 = (const float*)d_in[4];
    const float* b1  = (const float*)d_in[5];
    const float* g1  = (const float*)d_in[6];
    const float* be1 = (const float*)d_in[7];
    const float* W2  = (const float*)d_in[8];
    const float* as2 = (const float*)d_in[9];
    const float* ad2 = (const float*)d_in[10];
    const float* b2  = (const float*)d_in[11];
    const float* g2  = (const float*)d_in[12];
    const float* be2 = (const float*)d_in[13];
    const float* W3  = (const float*)d_in[14];
    const float* as3 = (const float*)d_in[15];
    const float* ad3 = (const float*)d_in[16];
    const float* b3  = (const float*)d_in[17];

    const int N = in_sizes[0] / 128;
    const int E = in_sizes[1] / 2;

    const int DPB  = cdiv(N, 256);         // dsts per bucket (<512 for u32 pack)
    const int NBLK = cdiv(E, CSR_CH);      // edge chunks (<=512)

    bf16*     hb    = (bf16*)d_ws;                      // N*128 bf16
    bf16*     aggb  = hb + (size_t)N * 128;             // N*128 bf16
    float*    asrc  = (float*)(aggb + (size_t)N * 128); // N*8
    float*    adst  = asrc + (size_t)N * 8;             // N*8
    unsigned* pairs = (unsigned*)(adst + (size_t)N * 8);// 256*REG u32
    int*      col   = (int*)(pairs + 256 * CSR_REG);    // 256*REG
    int2*     ptrSE = (int2*)(col + 256 * CSR_REG);     // N
    int*      histM = (int*)(ptrSE + N);                // NBLK*256
    int*      offT  = histM + (size_t)NBLK * 256;       // 256*NBLK
    int*      btot  = offT + (size_t)NBLK * 256;        // 256
    bf16*     h3b   = hb;                               // N*16 bf16 (layer 3)

    // ---- CSR build (atomic-free counting sort; reused by all 3 layers) ----
    csr_hist<<<NBLK, 256, 0, stream>>>(ei, E, DPB, histM);
    csr_colscan<<<256, 256, 0, stream>>>(histM, NBLK, offT, btot);
    csr_pair_scatter<<<NBLK, 256, 0, stream>>>(ei, E, DPB, offT, NBLK, pairs);
    csr_fine<<<256, 256, 0, stream>>>(pairs, btot, DPB, N, ptrSE, col);

    // ================= layer 1: 128 -> 8 heads x 16 =================
    gemm_mfma<float, 8><<<cdiv(N, 64), 256, 0, stream>>>(x, W1, as1, ad1, hb, asrc, adst, N);
    agg_ln_kernel<8, 16, 64><<<N, 64, 0, stream>>>(ptrSE, col, asrc, adst, hb, b1, g1, be1, aggb, N);

    // ================= layer 2: 128 -> 4 heads x 16 =================
    gemm_mfma<bf16, 4><<<cdiv(N, 64), 256, 0, stream>>>(aggb, W2, as2, ad2, hb, asrc, adst, N);
    agg_ln_kernel<4, 16, 32><<<cdiv(N, 2), 64, 0, stream>>>(ptrSE, col, asrc, adst, hb, b2, g2, be2, aggb, N);

    // ================= layer 3: 64 -> 1 head x 10, mean(=identity) ==
    gemm3_alpha<<<cdiv(N, 256), 256, 0, stream>>>(aggb, W3, as3, ad3, h3b, asrc, adst, N);
    agg_l3_final<<<cdiv(N, 16), 256, 0, stream>>>(ptrSE, col, asrc, adst, h3b, b3, (float*)d_out, N);
}

// Round 14
// 388.577 us; speedup vs baseline: 1.0432x; 1.0432x over previous
//
#include <hip/hip_runtime.h>
#include <hip/hip_bf16.h>
#include <math.h>

typedef __hip_bfloat16 bf16;
typedef __bf16 bf16x8 __attribute__((ext_vector_type(8)));
typedef float floatx4 __attribute__((ext_vector_type(4)));

__device__ __forceinline__ unsigned short f2bu(float f) {
    bf16 b = __float2bfloat16(f);
    return __builtin_bit_cast(unsigned short, b);
}
__device__ __forceinline__ float bu2f(unsigned short u) {
    return __uint_as_float(((unsigned)u) << 16);
}

// load PF packed bf16 as floats (16B/8B/4B vector loads)
template<int PF>
__device__ __forceinline__ void ldbfv(const unsigned short* p, float* v) {
    if constexpr (PF == 8) {
        uint4 u = *reinterpret_cast<const uint4*>(p);
        v[0] = __uint_as_float(u.x << 16); v[1] = __uint_as_float(u.x & 0xffff0000u);
        v[2] = __uint_as_float(u.y << 16); v[3] = __uint_as_float(u.y & 0xffff0000u);
        v[4] = __uint_as_float(u.z << 16); v[5] = __uint_as_float(u.z & 0xffff0000u);
        v[6] = __uint_as_float(u.w << 16); v[7] = __uint_as_float(u.w & 0xffff0000u);
    } else if constexpr (PF == 4) {
        uint2 u = *reinterpret_cast<const uint2*>(p);
        v[0] = __uint_as_float(u.x << 16); v[1] = __uint_as_float(u.x & 0xffff0000u);
        v[2] = __uint_as_float(u.y << 16); v[3] = __uint_as_float(u.y & 0xffff0000u);
    } else {
        unsigned u = *reinterpret_cast<const unsigned*>(p);
        v[0] = __uint_as_float(u << 16); v[1] = __uint_as_float(u & 0xffff0000u);
    }
}

// ====== MFMA GEMM + fused alpha: C[N,16H] = X[N,128] @ W[128,16H] ===========
// K=128 in LDS, one staging phase. Fragment layouts (m89/m91-verified).
template<typename XT, int H>
__global__ __launch_bounds__(256) void gemm_mfma(
    const XT* __restrict__ X, const float* __restrict__ W,
    const float* __restrict__ a_src, const float* __restrict__ a_dst,
    bf16* __restrict__ Hout, float* __restrict__ asrc, float* __restrict__ adst,
    int N)
{
    constexpr int M = H * 16;
    constexpr int KP = 136;
    constexpr int NT = M / 16;
    constexpr int HPQ = H / 4;
    __shared__ __align__(16) unsigned short Wt[M * KP];
    __shared__ __align__(16) unsigned short As[64 * KP];
    __shared__ float As_s[M], Ad_s[M];
    int tid = threadIdx.x;
    int r0 = blockIdx.x * 64;

    for (int i = tid; i < M; i += 256) { As_s[i] = a_src[i]; Ad_s[i] = a_dst[i]; }
    for (int idx = tid; idx < 128 * M; idx += 256) {
        int k = idx / M, m = idx % M;
        Wt[m * KP + k] = f2bu(W[idx]);
    }
    if constexpr (__is_same(XT, float)) {
        for (int idx = tid; idx < 64 * 32; idx += 256) {
            int row = idx >> 5, c4 = (idx & 31) * 4;
            int grow = r0 + row;
            float4 v = make_float4(0.f, 0.f, 0.f, 0.f);
            if (grow < N)
                v = *reinterpret_cast<const float4*>(X + (size_t)grow * 128 + c4);
            unsigned short* a = &As[row * KP + c4];
            a[0] = f2bu(v.x); a[1] = f2bu(v.y); a[2] = f2bu(v.z); a[3] = f2bu(v.w);
        }
    } else {
        for (int idx = tid; idx < 64 * 16; idx += 256) {
            int row = idx >> 4, c8 = (idx & 15) * 8;
            int grow = r0 + row;
            uint4 v = make_uint4(0u, 0u, 0u, 0u);
            if (grow < N)
                v = *reinterpret_cast<const uint4*>((const unsigned short*)X + (size_t)grow * 128 + c8);
            *reinterpret_cast<uint4*>(&As[row * KP + c8]) = v;
        }
    }
    __syncthreads();

    int w = tid >> 6, l = tid & 63, q = l >> 4, c = l & 15;
    floatx4 acc[NT];
    #pragma unroll
    for (int t = 0; t < NT; ++t) acc[t] = (floatx4){0.f, 0.f, 0.f, 0.f};

    #pragma unroll
    for (int kc = 0; kc < 4; ++kc) {
        bf16x8 a = *reinterpret_cast<const bf16x8*>(&As[(w * 16 + c) * KP + kc * 32 + q * 8]);
        #pragma unroll
        for (int t = 0; t < NT; ++t) {
            bf16x8 b = *reinterpret_cast<const bf16x8*>(&Wt[(t * 16 + c) * KP + kc * 32 + q * 8]);
            acc[t] = __builtin_amdgcn_mfma_f32_16x16x32_bf16(a, b, acc[t], 0, 0, 0);
        }
    }
    __syncthreads();
    #pragma unroll
    for (int t = 0; t < NT; ++t)
        #pragma unroll
        for (int r = 0; r < 4; ++r)
            As[(w * 16 + q * 4 + r) * KP + t * 16 + c] = f2bu(acc[t][r]);
    __syncthreads();
    for (int idx = tid; idx < 64 * (M / 8); idx += 256) {
        int row = idx / (M / 8), g = idx % (M / 8);
        int grow = r0 + row;
        if (grow < N)
            *reinterpret_cast<uint4*>(Hout + (size_t)grow * M + g * 8) =
                *reinterpret_cast<const uint4*>(&As[row * KP + g * 8]);
    }
    {
        int r = tid >> 2, qq = tid & 3;
        int grow = r0 + r;
        if (grow < N) {
            #pragma unroll
            for (int hh = 0; hh < HPQ; ++hh) {
                int hd = qq * HPQ + hh;
                float s1 = 0.f, s2 = 0.f;
                #pragma unroll
                for (int f = 0; f < 16; f += 2) {
                    unsigned u = *reinterpret_cast<const unsigned*>(&As[r * KP + hd * 16 + f]);
                    float v0 = __uint_as_float(u << 16);
                    float v1 = __uint_as_float(u & 0xffff0000u);
                    s1 += v0 * As_s[hd * 16 + f] + v1 * As_s[hd * 16 + f + 1];
                    s2 += v0 * Ad_s[hd * 16 + f] + v1 * Ad_s[hd * 16 + f + 1];
                }
                asrc[(size_t)grow * H + hd] = s1;
                adst[(size_t)grow * H + hd] = s2;
            }
        }
    }
}

// ============== atomic-free CSR build: counting sort by dst ==================
// Fixed per-bucket regions (CSR_REG slots, 24-sigma margin). Per-dst extents
// published as int2 ptrSE[d] = (start, end).
#define CSR_CH  4096
#define CSR_REG 8192

__global__ __launch_bounds__(256) void csr_hist(
    const int* __restrict__ ei, int E, int DPB, int* __restrict__ histM)
{
    __shared__ int cnt[256];
    int tid = threadIdx.x;
    cnt[tid] = 0;
    __syncthreads();
    int e0 = blockIdx.x * CSR_CH;
    int e1 = min(E, e0 + CSR_CH);
    for (int e = e0 + tid; e < e1; e += 256)
        atomicAdd(&cnt[ei[E + e] / DPB], 1);
    __syncthreads();
    histM[blockIdx.x * 256 + tid] = cnt[tid];
}

__global__ __launch_bounds__(256) void csr_colscan(
    const int* __restrict__ histM, int NBLK,
    int* __restrict__ offT, int* __restrict__ btot)
{
    __shared__ int sm[512];
    int b = blockIdx.x;
    int tid = threadIdx.x;
    int i0 = tid, i1 = tid + 256;
    sm[i0] = (i0 < NBLK) ? histM[i0 * 256 + b] : 0;
    sm[i1] = (i1 < NBLK) ? histM[i1 * 256 + b] : 0;
    __syncthreads();
    #pragma unroll
    for (int o = 1; o < 512; o <<= 1) {
        int t0 = (i0 >= o) ? sm[i0 - o] : 0;
        int t1 = (i1 >= o) ? sm[i1 - o] : 0;
        __syncthreads();
        sm[i0] += t0; sm[i1] += t1;
        __syncthreads();
    }
    if (i0 < NBLK) offT[b * NBLK + i0] = b * CSR_REG + ((i0 == 0) ? 0 : sm[i0 - 1]);
    if (i1 < NBLK) offT[b * NBLK + i1] = b * CSR_REG + sm[i1 - 1];
    if (tid == 0) btot[b] = sm[511];
}

__global__ __launch_bounds__(256) void csr_pair_scatter(
    const int* __restrict__ ei, int E, int DPB,
    const int* __restrict__ offT, int NBLK,
    unsigned* __restrict__ pairs)
{
    __shared__ int cnt[256];
    int tid = threadIdx.x;
    int blk = blockIdx.x;
    cnt[tid] = offT[tid * NBLK + blk];
    __syncthreads();
    int e0 = blk * CSR_CH;
    int e1 = min(E, e0 + CSR_CH);
    for (int e = e0 + tid; e < e1; e += 256) {
        int s = ei[e];
        int d = ei[E + e];
        int b = d / DPB;
        int dloc = d - b * DPB;
        int pos = atomicAdd(&cnt[b], 1);
        pairs[pos] = ((unsigned)dloc << 17) | (unsigned)s;
    }
}

__global__ __launch_bounds__(256) void csr_fine(
    const unsigned* __restrict__ pairs, const int* __restrict__ btot,
    int DPB, int N, int2* __restrict__ ptrSE, int* __restrict__ col)
{
    __shared__ int sm[512];
    __shared__ int off[512];
    int b = blockIdx.x;
    int tid = threadIdx.x;
    int base = b * CSR_REG;
    int tot = btot[b];
    int d0 = b * DPB;
    int i0 = tid, i1 = tid + 256;
    sm[i0] = 0; sm[i1] = 0;
    __syncthreads();
    for (int i = tid; i < tot; i += 256)
        atomicAdd(&sm[pairs[base + i] >> 17], 1);
    __syncthreads();
    #pragma unroll
    for (int o = 1; o < 512; o <<= 1) {
        int t0 = (i0 >= o) ? sm[i0 - o] : 0;
        int t1 = (i1 >= o) ? sm[i1 - o] : 0;
        __syncthreads();
        sm[i0] += t0; sm[i1] += t1;
        __syncthreads();
    }
    int s0e = base + ((i0 == 0) ? 0 : sm[i0 - 1]);
    int s1e = base + sm[i1 - 1];
    off[i0] = s0e;
    off[i1] = s1e;
    if (i0 < DPB && d0 + i0 < N) ptrSE[d0 + i0] = make_int2(s0e, base + sm[i0]);
    if (i1 < DPB && d0 + i1 < N) ptrSE[d0 + i1] = make_int2(s1e, base + sm[i1]);
    __syncthreads();
    for (int i = tid; i < tot; i += 256) {
        unsigned p = pairs[base + i];
        int pos = atomicAdd(&off[p >> 17], 1);
        col[pos] = (int)(p & 0x1FFFFu);
    }
}

// ------- CSR agg + bias + LN + ELU fused: LPD-lane subgroup per dst ---------
// PF = M/LPD features per lane, loaded as one 2*PF-byte vector. LPD=16 ->
// 4 dsts/wave, 16/block(256): ~2.4x fewer wave-inst per edge than LPD=64.
template<int M, int LPD>
__global__ __launch_bounds__(256) void agg_ln_kernel(
    const int2* __restrict__ ptrSE, const int* __restrict__ col,
    const float* __restrict__ asrc, const float* __restrict__ adst,
    const bf16* __restrict__ hb, const float* __restrict__ bias,
    const float* __restrict__ g, const float* __restrict__ be,
    bf16* __restrict__ out, int N)
{
    constexpr int PF = M / LPD;
    constexpr int H = M / 16;
    constexpr int DPBk = 256 / LPD;     // dsts per block
    int tid = threadIdx.x;
    int sub = tid / LPD;
    int j = tid % LPD;
    int d = blockIdx.x * DPBk + sub;
    if (d >= N) return;
    int f0 = j * PF;
    int hd = f0 / 16;
    int2 se = ptrSE[d];
    int e = se.x, end = se.y;
    float adst_h = adst[d * H + hd];
    const unsigned short* hw = (const unsigned short*)hb;

    float ac0[PF], ac1[PF];
    float dn0, dn1 = 0.f;
    { // self loop -> chain 0
        float lg = asrc[d * H + hd] + adst_h;
        lg = lg > 0.f ? lg : 0.2f * lg;
        float w = __expf(lg);
        float v[PF];
        ldbfv<PF>(hw + (size_t)d * M + f0, v);
        #pragma unroll
        for (int p = 0; p < PF; ++p) { ac0[p] = w * v[p]; ac1[p] = 0.f; }
        dn0 = w;
    }
    for (; e + 2 <= end; e += 2) {
        int s0 = col[e], s1 = col[e + 1];
        float l0 = asrc[s0 * H + hd];
        float l1 = asrc[s1 * H + hd];
        float v0[PF], v1[PF];
        ldbfv<PF>(hw + (size_t)s0 * M + f0, v0);
        ldbfv<PF>(hw + (size_t)s1 * M + f0, v1);
        l0 += adst_h; l0 = l0 > 0.f ? l0 : 0.2f * l0; float w0 = __expf(l0);
        l1 += adst_h; l1 = l1 > 0.f ? l1 : 0.2f * l1; float w1 = __expf(l1);
        #pragma unroll
        for (int p = 0; p < PF; ++p) {
            ac0[p] += w0 * v0[p];
            ac1[p] += w1 * v1[p];
        }
        dn0 += w0; dn1 += w1;
    }
    for (; e < end; ++e) {
        int s = col[e];
        float lg = asrc[s * H + hd] + adst_h;
        lg = lg > 0.f ? lg : 0.2f * lg;
        float w = __expf(lg);
        float v[PF];
        ldbfv<PF>(hw + (size_t)s * M + f0, v);
        #pragma unroll
        for (int p = 0; p < PF; ++p) ac0[p] += w * v[p];
        dn0 += w;
    }

    float rden = 1.f / (dn0 + dn1 + 1e-16f);
    float o[PF];
    float sm1 = 0.f, sm2 = 0.f;
    #pragma unroll
    for (int p = 0; p < PF; ++p) {
        o[p] = (ac0[p] + ac1[p]) * rden + bias[f0 + p];
        sm1 += o[p];
        sm2 += o[p] * o[p];
    }
    #pragma unroll
    for (int off = LPD / 2; off >= 1; off >>= 1) {
        sm1 += __shfl_xor(sm1, off, LPD);
        sm2 += __shfl_xor(sm2, off, LPD);
    }
    float mu = sm1 * (1.f / M);
    float var = sm2 * (1.f / M) - mu * mu;
    float inv = rsqrtf(var + 1e-5f);
    unsigned pk[PF / 2];
    #pragma unroll
    for (int p = 0; p < PF; p += 2) {
        float y0 = (o[p] - mu) * inv * g[f0 + p] + be[f0 + p];
        float y1 = (o[p + 1] - mu) * inv * g[f0 + p + 1] + be[f0 + p + 1];
        y0 = y0 > 0.f ? y0 : expm1f(y0);
        y1 = y1 > 0.f ? y1 : expm1f(y1);
        pk[p / 2] = (unsigned)f2bu(y0) | ((unsigned)f2bu(y1) << 16);
    }
    unsigned short* op = (unsigned short*)out + (size_t)d * M + f0;
    if constexpr (PF == 8)
        *reinterpret_cast<uint4*>(op) = make_uint4(pk[0], pk[1], pk[2], pk[3]);
    else if constexpr (PF == 4)
        *reinterpret_cast<uint2*>(op) = make_uint2(pk[0], pk[1]);
    else
        *reinterpret_cast<unsigned*>(op) = pk[0];
}

// ------- layer 3 GEMM (64->10) + alpha fused: one thread per node -----------
__global__ __launch_bounds__(256) void gemm3_alpha(
    const bf16* __restrict__ X, const float* __restrict__ W3,
    const float* __restrict__ av_src, const float* __restrict__ av_dst,
    bf16* __restrict__ h3, float* __restrict__ asrc, float* __restrict__ adst,
    int N)
{
    __shared__ float Wl[640];
    int tid = threadIdx.x;
    for (int i = tid; i < 640; i += 256) Wl[i] = W3[i];
    __syncthreads();
    int n = blockIdx.x * 256 + tid;
    if (n >= N) return;
    float h[10];
    #pragma unroll
    for (int j = 0; j < 10; ++j) h[j] = 0.f;
    const unsigned short* xr = (const unsigned short*)X + (size_t)n * 64;
    for (int k2 = 0; k2 < 32; ++k2) {
        unsigned u = *reinterpret_cast<const unsigned*>(xr + k2 * 2);
        float x0 = __uint_as_float(u << 16);
        float x1 = __uint_as_float(u & 0xffff0000u);
        #pragma unroll
        for (int j = 0; j < 10; ++j)
            h[j] += x0 * Wl[(k2 * 2) * 10 + j] + x1 * Wl[(k2 * 2 + 1) * 10 + j];
    }
    float s1 = 0.f, s2 = 0.f;
    unsigned short* hr = (unsigned short*)h3 + (size_t)n * 16;
    #pragma unroll
    for (int j = 0; j < 10; j += 2) {
        unsigned u = (unsigned)f2bu(h[j]) | ((unsigned)f2bu(h[j + 1]) << 16);
        *reinterpret_cast<unsigned*>(hr + j) = u;
    }
    #pragma unroll
    for (int j = 0; j < 10; ++j) {
        s1 += h[j] * av_src[j];
        s2 += h[j] * av_dst[j];
    }
    asrc[n] = s1;
    adst[n] = s2;
}

// --- layer-3 agg + bias + log_softmax fused: 16-lane subgroup per dst -------
__global__ __launch_bounds__(256) void agg_l3_final(
    const int2* __restrict__ ptrSE, const int* __restrict__ col,
    const float* __restrict__ asrc, const float* __restrict__ adst,
    const bf16* __restrict__ h, const float* __restrict__ b3,
    float* __restrict__ out, int N)
{
    int tid = threadIdx.x;
    int sub16 = tid >> 4;
    int j = tid & 15;
    int d = blockIdx.x * 16 + sub16;
    if (d >= N) return;
    const unsigned short* hu = (const unsigned short*)h;
    int2 se = ptrSE[d];
    int e = se.x, end = se.y;
    float adst_d = adst[d];
    float lg = asrc[d] + adst_d;
    lg = lg > 0.f ? lg : 0.2f * lg;
    float w = __expf(lg);
    bool act = j < 10;
    float a0 = act ? w * bu2f(hu[(size_t)d * 16 + j]) : 0.f;
    float a1 = 0.f, a2 = 0.f, a3 = 0.f;
    float d0 = w, d1 = 0.f, d2 = 0.f, d3 = 0.f;
    for (; e + 4 <= end; e += 4) {
        int s0 = col[e + 0], s1 = col[e + 1], s2 = col[e + 2], s3 = col[e + 3];
        float l0 = asrc[s0], l1 = asrc[s1], l2 = asrc[s2], l3 = asrc[s3];
        float v0 = act ? bu2f(hu[(size_t)s0 * 16 + j]) : 0.f;
        float v1 = act ? bu2f(hu[(size_t)s1 * 16 + j]) : 0.f;
        float v2 = act ? bu2f(hu[(size_t)s2 * 16 + j]) : 0.f;
        float v3 = act ? bu2f(hu[(size_t)s3 * 16 + j]) : 0.f;
        l0 += adst_d; l0 = l0 > 0.f ? l0 : 0.2f * l0; float w0 = __expf(l0);
        l1 += adst_d; l1 = l1 > 0.f ? l1 : 0.2f * l1; float w1 = __expf(l1);
        l2 += adst_d; l2 = l2 > 0.f ? l2 : 0.2f * l2; float w2 = __expf(l2);
        l3 += adst_d; l3 = l3 > 0.f ? l3 : 0.2f * l3; float w3 = __expf(l3);
        a0 += w0 * v0; a1 += w1 * v1; a2 += w2 * v2; a3 += w3 * v3;
        d0 += w0; d1 += w1; d2 += w2; d3 += w3;
    }
    for (; e < end; ++e) {
        int s = col[e];
        float l = asrc[s] + adst_d;
        l = l > 0.f ? l : 0.2f * l;
        float ww = __expf(l);
        if (act) a0 += ww * bu2f(hu[(size_t)s * 16 + j]);
        d0 += ww;
    }
    float den = d0 + d1 + d2 + d3;
    float v = (a0 + a1 + a2 + a3) / (den + 1e-16f);
    float lv = act ? v + b3[j] : -1e30f;
    float mx = lv;
    #pragma unroll
    for (int off = 1; off < 16; off <<= 1) mx = fmaxf(mx, __shfl_xor(mx, off, 16));
    float ev = act ? __expf(lv - mx) : 0.f;
    float se2 = ev;
    #pragma unroll
    for (int off = 1; off < 16; off <<= 1) se2 += __shfl_xor(se2, off, 16);
    float ls = mx + logf(se2);
    if (act) out[(size_t)d * 10 + j] = lv - ls;
}

static inline int cdiv(long a, long b) { return (int)((a + b - 1) / b); }

extern "C" void kernel_launch(void* const* d_in, const int* in_sizes, int n_in,
                              void* d_out, int out_size, void* d_ws, size_t ws_size,
                              hipStream_t stream)
{
    const float* x   = (const float*)d_in[0];
    const int*   ei  = (const int*)d_in[1];
    const float* W1  = (const float*)d_in[2];
    const float* as1 = (const float*)d_in[3];
    const float* ad1 = (const float*)d_in[4];
    const float* b1  = (const float*)d_in[5];
    const float* g1  = (const float*)d_in[6];
    const float* be1 = (const float*)d_in[7];
    const float* W2  = (const float*)d_in[8];
    const float* as2 = (const float*)d_in[9];
    const float* ad2 = (const float*)d_in[10];
    const float* b2  = (const float*)d_in[11];
    const float* g2  = (const float*)d_in[12];
    const float* be2 = (const float*)d_in[13];
    const float* W3  = (const float*)d_in[14];
    const float* as3 = (const float*)d_in[15];
    const float* ad3 = (const float*)d_in[16];
    const float* b3  = (const float*)d_in[17];

    const int N = in_sizes[0] / 128;
    const int E = in_sizes[1] / 2;

    const int DPB  = cdiv(N, 256);         // dsts per bucket (<512 for u32 pack)
    const int NBLK = cdiv(E, CSR_CH);      // edge chunks (<=512)

    bf16*     hb    = (bf16*)d_ws;                      // N*128 bf16
    bf16*     aggb  = hb + (size_t)N * 128;             // N*128 bf16
    float*    asrc  = (float*)(aggb + (size_t)N * 128); // N*8
    float*    adst  = asrc + (size_t)N * 8;             // N*8
    unsigned* pairs = (unsigned*)(adst + (size_t)N * 8);// 256*REG u32
    int*      col   = (int*)(pairs + 256 * CSR_REG);    // 256*REG
    int2*     ptrSE = (int2*)(col + 256 * CSR_REG);     // N
    int*      histM = (int*)(ptrSE + N);                // NBLK*256
    int*      offT  = histM + (size_t)NBLK * 256;       // 256*NBLK
    int*      btot  = offT + (size_t)NBLK * 256;        // 256
    bf16*     h3b   = hb;                               // N*16 bf16 (layer 3)

    // ---- CSR build (atomic-free counting sort; reused by all 3 layers) ----
    csr_hist<<<NBLK, 256, 0, stream>>>(ei, E, DPB, histM);
    csr_colscan<<<256, 256, 0, stream>>>(histM, NBLK, offT, btot);
    csr_pair_scatter<<<NBLK, 256, 0, stream>>>(ei, E, DPB, offT, NBLK, pairs);
    csr_fine<<<256, 256, 0, stream>>>(pairs, btot, DPB, N, ptrSE, col);

    // ================= layer 1: 128 -> 8 heads x 16 =================
    gemm_mfma<float, 8><<<cdiv(N, 64), 256, 0, stream>>>(x, W1, as1, ad1, hb, asrc, adst, N);
    agg_ln_kernel<128, 16><<<cdiv(N, 16), 256, 0, stream>>>(ptrSE, col, asrc, adst, hb, b1, g1, be1, aggb, N);

    // ================= layer 2: 128 -> 4 heads x 16 =================
    gemm_mfma<bf16, 4><<<cdiv(N, 64), 256, 0, stream>>>(aggb, W2, as2, ad2, hb, asrc, adst, N);
    agg_ln_kernel<64, 16><<<cdiv(N, 16), 256, 0, stream>>>(ptrSE, col, asrc, adst, hb, b2, g2, be2, aggb, N);

    // ================= layer 3: 64 -> 1 head x 10, mean(=identity) ==
    gemm3_alpha<<<cdiv(N, 256), 256, 0, stream>>>(aggb, W3, as3, ad3, h3b, asrc, adst, N);
    agg_l3_final<<<cdiv(N, 16), 256, 0, stream>>>(ptrSE, col, asrc, adst, h3b, b3, (float*)d_out, N);
}

// Round 15
// 378.542 us; speedup vs baseline: 1.0709x; 1.0265x over previous
//
#include <hip/hip_runtime.h>
#include <hip/hip_bf16.h>
#include <math.h>

typedef __hip_bfloat16 bf16;
typedef __bf16 bf16x8 __attribute__((ext_vector_type(8)));
typedef float floatx4 __attribute__((ext_vector_type(4)));

__device__ __forceinline__ unsigned short f2bu(float f) {
    bf16 b = __float2bfloat16(f);
    return __builtin_bit_cast(unsigned short, b);
}
__device__ __forceinline__ float bu2f(unsigned short u) {
    return __uint_as_float(((unsigned)u) << 16);
}

// load PF packed bf16 as floats (16B/8B/4B vector loads)
template<int PF>
__device__ __forceinline__ void ldbfv(const unsigned short* p, float* v) {
    if constexpr (PF == 8) {
        uint4 u = *reinterpret_cast<const uint4*>(p);
        v[0] = __uint_as_float(u.x << 16); v[1] = __uint_as_float(u.x & 0xffff0000u);
        v[2] = __uint_as_float(u.y << 16); v[3] = __uint_as_float(u.y & 0xffff0000u);
        v[4] = __uint_as_float(u.z << 16); v[5] = __uint_as_float(u.z & 0xffff0000u);
        v[6] = __uint_as_float(u.w << 16); v[7] = __uint_as_float(u.w & 0xffff0000u);
    } else if constexpr (PF == 4) {
        uint2 u = *reinterpret_cast<const uint2*>(p);
        v[0] = __uint_as_float(u.x << 16); v[1] = __uint_as_float(u.x & 0xffff0000u);
        v[2] = __uint_as_float(u.y << 16); v[3] = __uint_as_float(u.y & 0xffff0000u);
    } else {
        unsigned u = *reinterpret_cast<const unsigned*>(p);
        v[0] = __uint_as_float(u << 16); v[1] = __uint_as_float(u & 0xffff0000u);
    }
}

// ====== MFMA GEMM + fused alpha: C[N,16H] = X[N,128] @ W[128,16H] ===========
template<typename XT, int H>
__global__ __launch_bounds__(256) void gemm_mfma(
    const XT* __restrict__ X, const float* __restrict__ W,
    const float* __restrict__ a_src, const float* __restrict__ a_dst,
    bf16* __restrict__ Hout, float* __restrict__ asrc, float* __restrict__ adst,
    int N)
{
    constexpr int M = H * 16;
    constexpr int KP = 136;
    constexpr int NT = M / 16;
    constexpr int HPQ = H / 4;
    __shared__ __align__(16) unsigned short Wt[M * KP];
    __shared__ __align__(16) unsigned short As[64 * KP];
    __shared__ float As_s[M], Ad_s[M];
    int tid = threadIdx.x;
    int r0 = blockIdx.x * 64;

    for (int i = tid; i < M; i += 256) { As_s[i] = a_src[i]; Ad_s[i] = a_dst[i]; }
    for (int idx = tid; idx < 128 * M; idx += 256) {
        int k = idx / M, m = idx % M;
        Wt[m * KP + k] = f2bu(W[idx]);
    }
    if constexpr (__is_same(XT, float)) {
        for (int idx = tid; idx < 64 * 32; idx += 256) {
            int row = idx >> 5, c4 = (idx & 31) * 4;
            int grow = r0 + row;
            float4 v = make_float4(0.f, 0.f, 0.f, 0.f);
            if (grow < N)
                v = *reinterpret_cast<const float4*>(X + (size_t)grow * 128 + c4);
            unsigned short* a = &As[row * KP + c4];
            a[0] = f2bu(v.x); a[1] = f2bu(v.y); a[2] = f2bu(v.z); a[3] = f2bu(v.w);
        }
    } else {
        for (int idx = tid; idx < 64 * 16; idx += 256) {
            int row = idx >> 4, c8 = (idx & 15) * 8;
            int grow = r0 + row;
            uint4 v = make_uint4(0u, 0u, 0u, 0u);
            if (grow < N)
                v = *reinterpret_cast<const uint4*>((const unsigned short*)X + (size_t)grow * 128 + c8);
            *reinterpret_cast<uint4*>(&As[row * KP + c8]) = v;
        }
    }
    __syncthreads();

    int w = tid >> 6, l = tid & 63, q = l >> 4, c = l & 15;
    floatx4 acc[NT];
    #pragma unroll
    for (int t = 0; t < NT; ++t) acc[t] = (floatx4){0.f, 0.f, 0.f, 0.f};

    #pragma unroll
    for (int kc = 0; kc < 4; ++kc) {
        bf16x8 a = *reinterpret_cast<const bf16x8*>(&As[(w * 16 + c) * KP + kc * 32 + q * 8]);
        #pragma unroll
        for (int t = 0; t < NT; ++t) {
            bf16x8 b = *reinterpret_cast<const bf16x8*>(&Wt[(t * 16 + c) * KP + kc * 32 + q * 8]);
            acc[t] = __builtin_amdgcn_mfma_f32_16x16x32_bf16(a, b, acc[t], 0, 0, 0);
        }
    }
    __syncthreads();
    #pragma unroll
    for (int t = 0; t < NT; ++t)
        #pragma unroll
        for (int r = 0; r < 4; ++r)
            As[(w * 16 + q * 4 + r) * KP + t * 16 + c] = f2bu(acc[t][r]);
    __syncthreads();
    for (int idx = tid; idx < 64 * (M / 8); idx += 256) {
        int row = idx / (M / 8), g = idx % (M / 8);
        int grow = r0 + row;
        if (grow < N)
            *reinterpret_cast<uint4*>(Hout + (size_t)grow * M + g * 8) =
                *reinterpret_cast<const uint4*>(&As[row * KP + g * 8]);
    }
    {
        int r = tid >> 2, qq = tid & 3;
        int grow = r0 + r;
        if (grow < N) {
            #pragma unroll
            for (int hh = 0; hh < HPQ; ++hh) {
                int hd = qq * HPQ + hh;
                float s1 = 0.f, s2 = 0.f;
                #pragma unroll
                for (int f = 0; f < 16; f += 2) {
                    unsigned u = *reinterpret_cast<const unsigned*>(&As[r * KP + hd * 16 + f]);
                    float v0 = __uint_as_float(u << 16);
                    float v1 = __uint_as_float(u & 0xffff0000u);
                    s1 += v0 * As_s[hd * 16 + f] + v1 * As_s[hd * 16 + f + 1];
                    s2 += v0 * Ad_s[hd * 16 + f] + v1 * Ad_s[hd * 16 + f + 1];
                }
                asrc[(size_t)grow * H + hd] = s1;
                adst[(size_t)grow * H + hd] = s2;
            }
        }
    }
}

// ============== atomic-free CSR build: counting sort by dst ==================
#define CSR_CH  4096
#define CSR_REG 8192

__global__ __launch_bounds__(256) void csr_hist(
    const int* __restrict__ ei, int E, int DPB, int* __restrict__ histM)
{
    __shared__ int cnt[256];
    int tid = threadIdx.x;
    cnt[tid] = 0;
    __syncthreads();
    int e0 = blockIdx.x * CSR_CH;
    int e1 = min(E, e0 + CSR_CH);
    for (int e = e0 + tid; e < e1; e += 256)
        atomicAdd(&cnt[ei[E + e] / DPB], 1);
    __syncthreads();
    histM[blockIdx.x * 256 + tid] = cnt[tid];
}

__global__ __launch_bounds__(256) void csr_colscan(
    const int* __restrict__ histM, int NBLK,
    int* __restrict__ offT, int* __restrict__ btot)
{
    __shared__ int sm[512];
    int b = blockIdx.x;
    int tid = threadIdx.x;
    int i0 = tid, i1 = tid + 256;
    sm[i0] = (i0 < NBLK) ? histM[i0 * 256 + b] : 0;
    sm[i1] = (i1 < NBLK) ? histM[i1 * 256 + b] : 0;
    __syncthreads();
    #pragma unroll
    for (int o = 1; o < 512; o <<= 1) {
        int t0 = (i0 >= o) ? sm[i0 - o] : 0;
        int t1 = (i1 >= o) ? sm[i1 - o] : 0;
        __syncthreads();
        sm[i0] += t0; sm[i1] += t1;
        __syncthreads();
    }
    if (i0 < NBLK) offT[b * NBLK + i0] = b * CSR_REG + ((i0 == 0) ? 0 : sm[i0 - 1]);
    if (i1 < NBLK) offT[b * NBLK + i1] = b * CSR_REG + sm[i1 - 1];
    if (tid == 0) btot[b] = sm[511];
}

__global__ __launch_bounds__(256) void csr_pair_scatter(
    const int* __restrict__ ei, int E, int DPB,
    const int* __restrict__ offT, int NBLK,
    unsigned* __restrict__ pairs)
{
    __shared__ int cnt[256];
    int tid = threadIdx.x;
    int blk = blockIdx.x;
    cnt[tid] = offT[tid * NBLK + blk];
    __syncthreads();
    int e0 = blk * CSR_CH;
    int e1 = min(E, e0 + CSR_CH);
    for (int e = e0 + tid; e < e1; e += 256) {
        int s = ei[e];
        int d = ei[E + e];
        int b = d / DPB;
        int dloc = d - b * DPB;
        int pos = atomicAdd(&cnt[b], 1);
        pairs[pos] = ((unsigned)dloc << 17) | (unsigned)s;
    }
}

__global__ __launch_bounds__(256) void csr_fine(
    const unsigned* __restrict__ pairs, const int* __restrict__ btot,
    int DPB, int N, int2* __restrict__ ptrSE, int* __restrict__ col)
{
    __shared__ int sm[512];
    __shared__ int off[512];
    int b = blockIdx.x;
    int tid = threadIdx.x;
    int base = b * CSR_REG;
    int tot = btot[b];
    int d0 = b * DPB;
    int i0 = tid, i1 = tid + 256;
    sm[i0] = 0; sm[i1] = 0;
    __syncthreads();
    for (int i = tid; i < tot; i += 256)
        atomicAdd(&sm[pairs[base + i] >> 17], 1);
    __syncthreads();
    #pragma unroll
    for (int o = 1; o < 512; o <<= 1) {
        int t0 = (i0 >= o) ? sm[i0 - o] : 0;
        int t1 = (i1 >= o) ? sm[i1 - o] : 0;
        __syncthreads();
        sm[i0] += t0; sm[i1] += t1;
        __syncthreads();
    }
    int s0e = base + ((i0 == 0) ? 0 : sm[i0 - 1]);
    int s1e = base + sm[i1 - 1];
    off[i0] = s0e;
    off[i1] = s1e;
    if (i0 < DPB && d0 + i0 < N) ptrSE[d0 + i0] = make_int2(s0e, base + sm[i0]);
    if (i1 < DPB && d0 + i1 < N) ptrSE[d0 + i1] = make_int2(s1e, base + sm[i1]);
    __syncthreads();
    for (int i = tid; i < tot; i += 256) {
        unsigned p = pairs[base + i];
        int pos = atomicAdd(&off[p >> 17], 1);
        col[pos] = (int)(p & 0x1FFFFu);
    }
}

// ------- CSR agg + bias + LN + ELU fused: 16-lane subgroup per dst ----------
// PF = M/16 features per lane (one vector load per edge). 4-edge unroll with
// independent load chains -> 32 outstanding gathers per wave.
template<int M, int LPD>
__global__ __launch_bounds__(256) void agg_ln_kernel(
    const int2* __restrict__ ptrSE, const int* __restrict__ col,
    const float* __restrict__ asrc, const float* __restrict__ adst,
    const bf16* __restrict__ hb, const float* __restrict__ bias,
    const float* __restrict__ g, const float* __restrict__ be,
    bf16* __restrict__ out, int N)
{
    constexpr int PF = M / LPD;
    constexpr int H = M / 16;
    constexpr int DPBk = 256 / LPD;
    int tid = threadIdx.x;
    int sub = tid / LPD;
    int j = tid % LPD;
    int d = blockIdx.x * DPBk + sub;
    if (d >= N) return;
    int f0 = j * PF;
    int hd = f0 / 16;
    int2 se = ptrSE[d];
    int e = se.x, end = se.y;
    float adst_h = adst[d * H + hd];
    const unsigned short* hw = (const unsigned short*)hb;

    float ac0[PF], ac1[PF];
    float dn0, dn1 = 0.f;
    { // self loop -> chain 0
        float lg = asrc[d * H + hd] + adst_h;
        lg = lg > 0.f ? lg : 0.2f * lg;
        float w = __expf(lg);
        float v[PF];
        ldbfv<PF>(hw + (size_t)d * M + f0, v);
        #pragma unroll
        for (int p = 0; p < PF; ++p) { ac0[p] = w * v[p]; ac1[p] = 0.f; }
        dn0 = w;
    }
    for (; e + 4 <= end; e += 4) {
        int s0 = col[e], s1 = col[e + 1], s2 = col[e + 2], s3 = col[e + 3];
        float l0 = asrc[s0 * H + hd];
        float l1 = asrc[s1 * H + hd];
        float l2 = asrc[s2 * H + hd];
        float l3 = asrc[s3 * H + hd];
        float v0[PF], v1[PF], v2[PF], v3[PF];
        ldbfv<PF>(hw + (size_t)s0 * M + f0, v0);
        ldbfv<PF>(hw + (size_t)s1 * M + f0, v1);
        ldbfv<PF>(hw + (size_t)s2 * M + f0, v2);
        ldbfv<PF>(hw + (size_t)s3 * M + f0, v3);
        l0 += adst_h; l0 = l0 > 0.f ? l0 : 0.2f * l0; float w0 = __expf(l0);
        l1 += adst_h; l1 = l1 > 0.f ? l1 : 0.2f * l1; float w1 = __expf(l1);
        l2 += adst_h; l2 = l2 > 0.f ? l2 : 0.2f * l2; float w2 = __expf(l2);
        l3 += adst_h; l3 = l3 > 0.f ? l3 : 0.2f * l3; float w3 = __expf(l3);
        #pragma unroll
        for (int p = 0; p < PF; ++p) {
            ac0[p] += w0 * v0[p];
            ac1[p] += w1 * v1[p];
            ac0[p] += w2 * v2[p];
            ac1[p] += w3 * v3[p];
        }
        dn0 += w0 + w2; dn1 += w1 + w3;
    }
    for (; e < end; ++e) {
        int s = col[e];
        float lg = asrc[s * H + hd] + adst_h;
        lg = lg > 0.f ? lg : 0.2f * lg;
        float w = __expf(lg);
        float v[PF];
        ldbfv<PF>(hw + (size_t)s * M + f0, v);
        #pragma unroll
        for (int p = 0; p < PF; ++p) ac0[p] += w * v[p];
        dn0 += w;
    }

    float rden = 1.f / (dn0 + dn1 + 1e-16f);
    float o[PF];
    float sm1 = 0.f, sm2 = 0.f;
    #pragma unroll
    for (int p = 0; p < PF; ++p) {
        o[p] = (ac0[p] + ac1[p]) * rden + bias[f0 + p];
        sm1 += o[p];
        sm2 += o[p] * o[p];
    }
    #pragma unroll
    for (int off = LPD / 2; off >= 1; off >>= 1) {
        sm1 += __shfl_xor(sm1, off, LPD);
        sm2 += __shfl_xor(sm2, off, LPD);
    }
    float mu = sm1 * (1.f / M);
    float var = sm2 * (1.f / M) - mu * mu;
    float inv = rsqrtf(var + 1e-5f);
    unsigned pk[PF / 2];
    #pragma unroll
    for (int p = 0; p < PF; p += 2) {
        float y0 = (o[p] - mu) * inv * g[f0 + p] + be[f0 + p];
        float y1 = (o[p + 1] - mu) * inv * g[f0 + p + 1] + be[f0 + p + 1];
        y0 = y0 > 0.f ? y0 : expm1f(y0);
        y1 = y1 > 0.f ? y1 : expm1f(y1);
        pk[p / 2] = (unsigned)f2bu(y0) | ((unsigned)f2bu(y1) << 16);
    }
    unsigned short* op = (unsigned short*)out + (size_t)d * M + f0;
    if constexpr (PF == 8)
        *reinterpret_cast<uint4*>(op) = make_uint4(pk[0], pk[1], pk[2], pk[3]);
    else if constexpr (PF == 4)
        *reinterpret_cast<uint2*>(op) = make_uint2(pk[0], pk[1]);
    else
        *reinterpret_cast<unsigned*>(op) = pk[0];
}

// ------- layer 3 GEMM (64->10) + alpha fused: one thread per node -----------
__global__ __launch_bounds__(256) void gemm3_alpha(
    const bf16* __restrict__ X, const float* __restrict__ W3,
    const float* __restrict__ av_src, const float* __restrict__ av_dst,
    bf16* __restrict__ h3, float* __restrict__ asrc, float* __restrict__ adst,
    int N)
{
    __shared__ float Wl[640];
    int tid = threadIdx.x;
    for (int i = tid; i < 640; i += 256) Wl[i] = W3[i];
    __syncthreads();
    int n = blockIdx.x * 256 + tid;
    if (n >= N) return;
    float h[10];
    #pragma unroll
    for (int j = 0; j < 10; ++j) h[j] = 0.f;
    const unsigned short* xr = (const unsigned short*)X + (size_t)n * 64;
    for (int k2 = 0; k2 < 32; ++k2) {
        unsigned u = *reinterpret_cast<const unsigned*>(xr + k2 * 2);
        float x0 = __uint_as_float(u << 16);
        float x1 = __uint_as_float(u & 0xffff0000u);
        #pragma unroll
        for (int j = 0; j < 10; ++j)
            h[j] += x0 * Wl[(k2 * 2) * 10 + j] + x1 * Wl[(k2 * 2 + 1) * 10 + j];
    }
    float s1 = 0.f, s2 = 0.f;
    unsigned short* hr = (unsigned short*)h3 + (size_t)n * 16;
    #pragma unroll
    for (int j = 0; j < 10; j += 2) {
        unsigned u = (unsigned)f2bu(h[j]) | ((unsigned)f2bu(h[j + 1]) << 16);
        *reinterpret_cast<unsigned*>(hr + j) = u;
    }
    #pragma unroll
    for (int j = 0; j < 10; ++j) {
        s1 += h[j] * av_src[j];
        s2 += h[j] * av_dst[j];
    }
    asrc[n] = s1;
    adst[n] = s2;
}

// --- layer-3 agg + bias + log_softmax fused: 16-lane subgroup per dst -------
__global__ __launch_bounds__(256) void agg_l3_final(
    const int2* __restrict__ ptrSE, const int* __restrict__ col,
    const float* __restrict__ asrc, const float* __restrict__ adst,
    const bf16* __restrict__ h, const float* __restrict__ b3,
    float* __restrict__ out, int N)
{
    int tid = threadIdx.x;
    int sub16 = tid >> 4;
    int j = tid & 15;
    int d = blockIdx.x * 16 + sub16;
    if (d >= N) return;
    const unsigned short* hu = (const unsigned short*)h;
    int2 se = ptrSE[d];
    int e = se.x, end = se.y;
    float adst_d = adst[d];
    float lg = asrc[d] + adst_d;
    lg = lg > 0.f ? lg : 0.2f * lg;
    float w = __expf(lg);
    bool act = j < 10;
    float a0 = act ? w * bu2f(hu[(size_t)d * 16 + j]) : 0.f;
    float a1 = 0.f, a2 = 0.f, a3 = 0.f;
    float d0 = w, d1 = 0.f, d2 = 0.f, d3 = 0.f;
    for (; e + 4 <= end; e += 4) {
        int s0 = col[e + 0], s1 = col[e + 1], s2 = col[e + 2], s3 = col[e + 3];
        float l0 = asrc[s0], l1 = asrc[s1], l2 = asrc[s2], l3 = asrc[s3];
        float v0 = act ? bu2f(hu[(size_t)s0 * 16 + j]) : 0.f;
        float v1 = act ? bu2f(hu[(size_t)s1 * 16 + j]) : 0.f;
        float v2 = act ? bu2f(hu[(size_t)s2 * 16 + j]) : 0.f;
        float v3 = act ? bu2f(hu[(size_t)s3 * 16 + j]) : 0.f;
        l0 += adst_d; l0 = l0 > 0.f ? l0 : 0.2f * l0; float w0 = __expf(l0);
        l1 += adst_d; l1 = l1 > 0.f ? l1 : 0.2f * l1; float w1 = __expf(l1);
        l2 += adst_d; l2 = l2 > 0.f ? l2 : 0.2f * l2; float w2 = __expf(l2);
        l3 += adst_d; l3 = l3 > 0.f ? l3 : 0.2f * l3; float w3 = __expf(l3);
        a0 += w0 * v0; a1 += w1 * v1; a2 += w2 * v2; a3 += w3 * v3;
        d0 += w0; d1 += w1; d2 += w2; d3 += w3;
    }
    for (; e < end; ++e) {
        int s = col[e];
        float l = asrc[s] + adst_d;
        l = l > 0.f ? l : 0.2f * l;
        float ww = __expf(l);
        if (act) a0 += ww * bu2f(hu[(size_t)s * 16 + j]);
        d0 += ww;
    }
    float den = d0 + d1 + d2 + d3;
    float v = (a0 + a1 + a2 + a3) / (den + 1e-16f);
    float lv = act ? v + b3[j] : -1e30f;
    float mx = lv;
    #pragma unroll
    for (int off = 1; off < 16; off <<= 1) mx = fmaxf(mx, __shfl_xor(mx, off, 16));
    float ev = act ? __expf(lv - mx) : 0.f;
    float se2 = ev;
    #pragma unroll
    for (int off = 1; off < 16; off <<= 1) se2 += __shfl_xor(se2, off, 16);
    float ls = mx + logf(se2);
    if (act) out[(size_t)d * 10 + j] = lv - ls;
}

static inline int cdiv(long a, long b) { return (int)((a + b - 1) / b); }

extern "C" void kernel_launch(void* const* d_in, const int* in_sizes, int n_in,
                              void* d_out, int out_size, void* d_ws, size_t ws_size,
                              hipStream_t stream)
{
    const float* x   = (const float*)d_in[0];
    const int*   ei  = (const int*)d_in[1];
    const float* W1  = (const float*)d_in[2];
    const float* as1 = (const float*)d_in[3];
    const float* ad1 = (const float*)d_in[4];
    const float* b1  = (const float*)d_in[5];
    const float* g1  = (const float*)d_in[6];
    const float* be1 = (const float*)d_in[7];
    const float* W2  = (const float*)d_in[8];
    const float* as2 = (const float*)d_in[9];
    const float* ad2 = (const float*)d_in[10];
    const float* b2  = (const float*)d_in[11];
    const float* g2  = (const float*)d_in[12];
    const float* be2 = (const float*)d_in[13];
    const float* W3  = (const float*)d_in[14];
    const float* as3 = (const float*)d_in[15];
    const float* ad3 = (const float*)d_in[16];
    const float* b3  = (const float*)d_in[17];

    const int N = in_sizes[0] / 128;
    const int E = in_sizes[1] / 2;

    const int DPB  = cdiv(N, 256);
    const int NBLK = cdiv(E, CSR_CH);

    bf16*     hb    = (bf16*)d_ws;                      // N*128 bf16
    bf16*     aggb  = hb + (size_t)N * 128;             // N*128 bf16
    float*    asrc  = (float*)(aggb + (size_t)N * 128); // N*8
    float*    adst  = asrc + (size_t)N * 8;             // N*8
    unsigned* pairs = (unsigned*)(adst + (size_t)N * 8);// 256*REG u32
    int*      col   = (int*)(pairs + 256 * CSR_REG);    // 256*REG
    int2*     ptrSE = (int2*)(col + 256 * CSR_REG);     // N
    int*      histM = (int*)(ptrSE + N);                // NBLK*256
    int*      offT  = histM + (size_t)NBLK * 256;       // 256*NBLK
    int*      btot  = offT + (size_t)NBLK * 256;        // 256
    bf16*     h3b   = hb;                               // N*16 bf16 (layer 3)

    // ---- CSR build (atomic-free counting sort; reused by all 3 layers) ----
    csr_hist<<<NBLK, 256, 0, stream>>>(ei, E, DPB, histM);
    csr_colscan<<<256, 256, 0, stream>>>(histM, NBLK, offT, btot);
    csr_pair_scatter<<<NBLK, 256, 0, stream>>>(ei, E, DPB, offT, NBLK, pairs);
    csr_fine<<<256, 256, 0, stream>>>(pairs, btot, DPB, N, ptrSE, col);

    // ================= layer 1: 128 -> 8 heads x 16 =================
    gemm_mfma<float, 8><<<cdiv(N, 64), 256, 0, stream>>>(x, W1, as1, ad1, hb, asrc, adst, N);
    agg_ln_kernel<128, 16><<<cdiv(N, 16), 256, 0, stream>>>(ptrSE, col, asrc, adst, hb, b1, g1, be1, aggb, N);

    // ================= layer 2: 128 -> 4 heads x 16 =================
    gemm_mfma<bf16, 4><<<cdiv(N, 64), 256, 0, stream>>>(aggb, W2, as2, ad2, hb, asrc, adst, N);
    agg_ln_kernel<64, 16><<<cdiv(N, 16), 256, 0, stream>>>(ptrSE, col, asrc, adst, hb, b2, g2, be2, aggb, N);

    // ================= layer 3: 64 -> 1 head x 10, mean(=identity) ==
    gemm3_alpha<<<cdiv(N, 256), 256, 0, stream>>>(aggb, W3, as3, ad3, h3b, asrc, adst, N);
    agg_l3_final<<<cdiv(N, 16), 256, 0, stream>>>(ptrSE, col, asrc, adst, h3b, b3, (float*)d_out, N);
}

// Round 16
// 375.897 us; speedup vs baseline: 1.0784x; 1.0070x over previous
//
#include <hip/hip_runtime.h>
#include <hip/hip_bf16.h>
#include <math.h>

typedef __hip_bfloat16 bf16;
typedef __bf16 bf16x8 __attribute__((ext_vector_type(8)));
typedef float floatx4 __attribute__((ext_vector_type(4)));

#define CSR_CH  4096
#define CSR_REG 8192

__device__ __forceinline__ unsigned short f2bu(float f) {
    bf16 b = __float2bfloat16(f);
    return __builtin_bit_cast(unsigned short, b);
}
__device__ __forceinline__ float bu2f(unsigned short u) {
    return __uint_as_float(((unsigned)u) << 16);
}

// load PF packed bf16 as floats (16B/8B/4B vector loads)
template<int PF>
__device__ __forceinline__ void ldbfv(const unsigned short* p, float* v) {
    if constexpr (PF == 8) {
        uint4 u = *reinterpret_cast<const uint4*>(p);
        v[0] = __uint_as_float(u.x << 16); v[1] = __uint_as_float(u.x & 0xffff0000u);
        v[2] = __uint_as_float(u.y << 16); v[3] = __uint_as_float(u.y & 0xffff0000u);
        v[4] = __uint_as_float(u.z << 16); v[5] = __uint_as_float(u.z & 0xffff0000u);
        v[6] = __uint_as_float(u.w << 16); v[7] = __uint_as_float(u.w & 0xffff0000u);
    } else if constexpr (PF == 4) {
        uint2 u = *reinterpret_cast<const uint2*>(p);
        v[0] = __uint_as_float(u.x << 16); v[1] = __uint_as_float(u.x & 0xffff0000u);
        v[2] = __uint_as_float(u.y << 16); v[3] = __uint_as_float(u.y & 0xffff0000u);
    } else {
        unsigned u = *reinterpret_cast<const unsigned*>(p);
        v[0] = __uint_as_float(u << 16); v[1] = __uint_as_float(u & 0xffff0000u);
    }
}

// ====== MFMA GEMM + fused alpha (+ optional csr_hist blocks) ================
// blocks [0,NG): GEMM; blocks [NG, NG+NBLK): csr_hist (aliases Wt LDS).
template<typename XT, int H>
__global__ __launch_bounds__(256) void gemm_mfma(
    const XT* __restrict__ X, const float* __restrict__ W,
    const float* __restrict__ a_src, const float* __restrict__ a_dst,
    bf16* __restrict__ Hout, float* __restrict__ asrc, float* __restrict__ adst,
    int N, int NG, const int* __restrict__ ei, int E, int DPB,
    int* __restrict__ histM)
{
    constexpr int M = H * 16;
    constexpr int KP = 136;
    constexpr int NT = M / 16;
    constexpr int HPQ = H / 4;
    __shared__ __align__(16) unsigned short Wt[M * KP];
    __shared__ __align__(16) unsigned short As[64 * KP];
    __shared__ float As_s[M], Ad_s[M];
    int tid = threadIdx.x;

    if (blockIdx.x >= NG) {          // ---- csr_hist path ----
        int* cnt = (int*)Wt;
        cnt[tid] = 0;
        __syncthreads();
        int blk = blockIdx.x - NG;
        int e0 = blk * CSR_CH;
        int e1 = min(E, e0 + CSR_CH);
        for (int e = e0 + tid; e < e1; e += 256)
            atomicAdd(&cnt[ei[E + e] / DPB], 1);
        __syncthreads();
        histM[blk * 256 + tid] = cnt[tid];
        return;
    }

    int r0 = blockIdx.x * 64;
    for (int i = tid; i < M; i += 256) { As_s[i] = a_src[i]; Ad_s[i] = a_dst[i]; }
    for (int idx = tid; idx < 128 * M; idx += 256) {
        int k = idx / M, m = idx % M;
        Wt[m * KP + k] = f2bu(W[idx]);
    }
    if constexpr (__is_same(XT, float)) {
        for (int idx = tid; idx < 64 * 32; idx += 256) {
            int row = idx >> 5, c4 = (idx & 31) * 4;
            int grow = r0 + row;
            float4 v = make_float4(0.f, 0.f, 0.f, 0.f);
            if (grow < N)
                v = *reinterpret_cast<const float4*>(X + (size_t)grow * 128 + c4);
            unsigned short* a = &As[row * KP + c4];
            a[0] = f2bu(v.x); a[1] = f2bu(v.y); a[2] = f2bu(v.z); a[3] = f2bu(v.w);
        }
    } else {
        for (int idx = tid; idx < 64 * 16; idx += 256) {
            int row = idx >> 4, c8 = (idx & 15) * 8;
            int grow = r0 + row;
            uint4 v = make_uint4(0u, 0u, 0u, 0u);
            if (grow < N)
                v = *reinterpret_cast<const uint4*>((const unsigned short*)X + (size_t)grow * 128 + c8);
            *reinterpret_cast<uint4*>(&As[row * KP + c8]) = v;
        }
    }
    __syncthreads();

    int w = tid >> 6, l = tid & 63, q = l >> 4, c = l & 15;
    floatx4 acc[NT];
    #pragma unroll
    for (int t = 0; t < NT; ++t) acc[t] = (floatx4){0.f, 0.f, 0.f, 0.f};

    #pragma unroll
    for (int kc = 0; kc < 4; ++kc) {
        bf16x8 a = *reinterpret_cast<const bf16x8*>(&As[(w * 16 + c) * KP + kc * 32 + q * 8]);
        #pragma unroll
        for (int t = 0; t < NT; ++t) {
            bf16x8 b = *reinterpret_cast<const bf16x8*>(&Wt[(t * 16 + c) * KP + kc * 32 + q * 8]);
            acc[t] = __builtin_amdgcn_mfma_f32_16x16x32_bf16(a, b, acc[t], 0, 0, 0);
        }
    }
    __syncthreads();
    #pragma unroll
    for (int t = 0; t < NT; ++t)
        #pragma unroll
        for (int r = 0; r < 4; ++r)
            As[(w * 16 + q * 4 + r) * KP + t * 16 + c] = f2bu(acc[t][r]);
    __syncthreads();
    for (int idx = tid; idx < 64 * (M / 8); idx += 256) {
        int row = idx / (M / 8), g = idx % (M / 8);
        int grow = r0 + row;
        if (grow < N)
            *reinterpret_cast<uint4*>(Hout + (size_t)grow * M + g * 8) =
                *reinterpret_cast<const uint4*>(&As[row * KP + g * 8]);
    }
    {
        int r = tid >> 2, qq = tid & 3;
        int grow = r0 + r;
        if (grow < N) {
            #pragma unroll
            for (int hh = 0; hh < HPQ; ++hh) {
                int hd = qq * HPQ + hh;
                float s1 = 0.f, s2 = 0.f;
                #pragma unroll
                for (int f = 0; f < 16; f += 2) {
                    unsigned u = *reinterpret_cast<const unsigned*>(&As[r * KP + hd * 16 + f]);
                    float v0 = __uint_as_float(u << 16);
                    float v1 = __uint_as_float(u & 0xffff0000u);
                    s1 += v0 * As_s[hd * 16 + f] + v1 * As_s[hd * 16 + f + 1];
                    s2 += v0 * Ad_s[hd * 16 + f] + v1 * Ad_s[hd * 16 + f + 1];
                }
                asrc[(size_t)grow * H + hd] = s1;
                adst[(size_t)grow * H + hd] = s2;
            }
        }
    }
}

// ============== atomic-free CSR build (hist fused into gemm1) ================
__global__ __launch_bounds__(256) void csr_colscan(
    const int* __restrict__ histM, int NBLK,
    int* __restrict__ offT, int* __restrict__ btot)
{
    __shared__ int sm[512];
    int b = blockIdx.x;
    int tid = threadIdx.x;
    int i0 = tid, i1 = tid + 256;
    sm[i0] = (i0 < NBLK) ? histM[i0 * 256 + b] : 0;
    sm[i1] = (i1 < NBLK) ? histM[i1 * 256 + b] : 0;
    __syncthreads();
    #pragma unroll
    for (int o = 1; o < 512; o <<= 1) {
        int t0 = (i0 >= o) ? sm[i0 - o] : 0;
        int t1 = (i1 >= o) ? sm[i1 - o] : 0;
        __syncthreads();
        sm[i0] += t0; sm[i1] += t1;
        __syncthreads();
    }
    if (i0 < NBLK) offT[b * NBLK + i0] = b * CSR_REG + ((i0 == 0) ? 0 : sm[i0 - 1]);
    if (i1 < NBLK) offT[b * NBLK + i1] = b * CSR_REG + sm[i1 - 1];
    if (tid == 0) btot[b] = sm[511];
}

__global__ __launch_bounds__(256) void csr_pair_scatter(
    const int* __restrict__ ei, int E, int DPB,
    const int* __restrict__ offT, int NBLK,
    unsigned* __restrict__ pairs)
{
    __shared__ int cnt[256];
    int tid = threadIdx.x;
    int blk = blockIdx.x;
    cnt[tid] = offT[tid * NBLK + blk];
    __syncthreads();
    int e0 = blk * CSR_CH;
    int e1 = min(E, e0 + CSR_CH);
    for (int e = e0 + tid; e < e1; e += 256) {
        int s = ei[e];
        int d = ei[E + e];
        int b = d / DPB;
        int dloc = d - b * DPB;
        int pos = atomicAdd(&cnt[b], 1);
        pairs[pos] = ((unsigned)dloc << 17) | (unsigned)s;
    }
}

__global__ __launch_bounds__(256) void csr_fine(
    const unsigned* __restrict__ pairs, const int* __restrict__ btot,
    int DPB, int N, int2* __restrict__ ptrSE, int* __restrict__ col)
{
    __shared__ int sm[512];
    __shared__ int off[512];
    int b = blockIdx.x;
    int tid = threadIdx.x;
    int base = b * CSR_REG;
    int tot = btot[b];
    int d0 = b * DPB;
    int i0 = tid, i1 = tid + 256;
    sm[i0] = 0; sm[i1] = 0;
    __syncthreads();
    for (int i = tid; i < tot; i += 256)
        atomicAdd(&sm[pairs[base + i] >> 17], 1);
    __syncthreads();
    #pragma unroll
    for (int o = 1; o < 512; o <<= 1) {
        int t0 = (i0 >= o) ? sm[i0 - o] : 0;
        int t1 = (i1 >= o) ? sm[i1 - o] : 0;
        __syncthreads();
        sm[i0] += t0; sm[i1] += t1;
        __syncthreads();
    }
    int s0e = base + ((i0 == 0) ? 0 : sm[i0 - 1]);
    int s1e = base + sm[i1 - 1];
    off[i0] = s0e;
    off[i1] = s1e;
    if (i0 < DPB && d0 + i0 < N) ptrSE[d0 + i0] = make_int2(s0e, base + sm[i0]);
    if (i1 < DPB && d0 + i1 < N) ptrSE[d0 + i1] = make_int2(s1e, base + sm[i1]);
    __syncthreads();
    for (int i = tid; i < tot; i += 256) {
        unsigned p = pairs[base + i];
        int pos = atomicAdd(&off[p >> 17], 1);
        col[pos] = (int)(p & 0x1FFFFu);
    }
}

// ------- layer-1 CSR agg + bias + LN + ELU: 16-lane subgroup per dst --------
template<int M, int LPD>
__global__ __launch_bounds__(256) void agg_ln_kernel(
    const int2* __restrict__ ptrSE, const int* __restrict__ col,
    const float* __restrict__ asrc, const float* __restrict__ adst,
    const bf16* __restrict__ hb, const float* __restrict__ bias,
    const float* __restrict__ g, const float* __restrict__ be,
    bf16* __restrict__ out, int N)
{
    constexpr int PF = M / LPD;
    constexpr int H = M / 16;
    constexpr int DPBk = 256 / LPD;
    int tid = threadIdx.x;
    int sub = tid / LPD;
    int j = tid % LPD;
    int d = blockIdx.x * DPBk + sub;
    if (d >= N) return;
    int f0 = j * PF;
    int hd = f0 / 16;
    int2 se = ptrSE[d];
    int e = se.x, end = se.y;
    float adst_h = adst[d * H + hd];
    const unsigned short* hw = (const unsigned short*)hb;

    float ac0[PF], ac1[PF];
    float dn0, dn1 = 0.f;
    {
        float lg = asrc[d * H + hd] + adst_h;
        lg = lg > 0.f ? lg : 0.2f * lg;
        float w = __expf(lg);
        float v[PF];
        ldbfv<PF>(hw + (size_t)d * M + f0, v);
        #pragma unroll
        for (int p = 0; p < PF; ++p) { ac0[p] = w * v[p]; ac1[p] = 0.f; }
        dn0 = w;
    }
    for (; e + 4 <= end; e += 4) {
        int s0 = col[e], s1 = col[e + 1], s2 = col[e + 2], s3 = col[e + 3];
        float l0 = asrc[s0 * H + hd];
        float l1 = asrc[s1 * H + hd];
        float l2 = asrc[s2 * H + hd];
        float l3 = asrc[s3 * H + hd];
        float v0[PF], v1[PF], v2[PF], v3[PF];
        ldbfv<PF>(hw + (size_t)s0 * M + f0, v0);
        ldbfv<PF>(hw + (size_t)s1 * M + f0, v1);
        ldbfv<PF>(hw + (size_t)s2 * M + f0, v2);
        ldbfv<PF>(hw + (size_t)s3 * M + f0, v3);
        l0 += adst_h; l0 = l0 > 0.f ? l0 : 0.2f * l0; float w0 = __expf(l0);
        l1 += adst_h; l1 = l1 > 0.f ? l1 : 0.2f * l1; float w1 = __expf(l1);
        l2 += adst_h; l2 = l2 > 0.f ? l2 : 0.2f * l2; float w2 = __expf(l2);
        l3 += adst_h; l3 = l3 > 0.f ? l3 : 0.2f * l3; float w3 = __expf(l3);
        #pragma unroll
        for (int p = 0; p < PF; ++p) {
            ac0[p] += w0 * v0[p];
            ac1[p] += w1 * v1[p];
            ac0[p] += w2 * v2[p];
            ac1[p] += w3 * v3[p];
        }
        dn0 += w0 + w2; dn1 += w1 + w3;
    }
    for (; e < end; ++e) {
        int s = col[e];
        float lg = asrc[s * H + hd] + adst_h;
        lg = lg > 0.f ? lg : 0.2f * lg;
        float w = __expf(lg);
        float v[PF];
        ldbfv<PF>(hw + (size_t)s * M + f0, v);
        #pragma unroll
        for (int p = 0; p < PF; ++p) ac0[p] += w * v[p];
        dn0 += w;
    }

    float rden = 1.f / (dn0 + dn1 + 1e-16f);
    float o[PF];
    float sm1 = 0.f, sm2 = 0.f;
    #pragma unroll
    for (int p = 0; p < PF; ++p) {
        o[p] = (ac0[p] + ac1[p]) * rden + bias[f0 + p];
        sm1 += o[p];
        sm2 += o[p] * o[p];
    }
    #pragma unroll
    for (int off = LPD / 2; off >= 1; off >>= 1) {
        sm1 += __shfl_xor(sm1, off, LPD);
        sm2 += __shfl_xor(sm2, off, LPD);
    }
    float mu = sm1 * (1.f / M);
    float var = sm2 * (1.f / M) - mu * mu;
    float inv = rsqrtf(var + 1e-5f);
    unsigned pk[PF / 2];
    #pragma unroll
    for (int p = 0; p < PF; p += 2) {
        float y0 = (o[p] - mu) * inv * g[f0 + p] + be[f0 + p];
        float y1 = (o[p + 1] - mu) * inv * g[f0 + p + 1] + be[f0 + p + 1];
        y0 = y0 > 0.f ? y0 : expm1f(y0);
        y1 = y1 > 0.f ? y1 : expm1f(y1);
        pk[p / 2] = (unsigned)f2bu(y0) | ((unsigned)f2bu(y1) << 16);
    }
    unsigned short* op = (unsigned short*)out + (size_t)d * M + f0;
    if constexpr (PF == 8)
        *reinterpret_cast<uint4*>(op) = make_uint4(pk[0], pk[1], pk[2], pk[3]);
    else if constexpr (PF == 4)
        *reinterpret_cast<uint2*>(op) = make_uint2(pk[0], pk[1]);
    else
        *reinterpret_cast<unsigned*>(op) = pk[0];
}

// --- layer-2 agg + LN + ELU + fused gemm3 (64->10) + alpha3 -----------------
// 16-lane subgroup per dst; after LN, per-lane W3 partials + width-16
// butterfly give the full 10-logit h3 row; lane 0 writes h3 + alphas.
__global__ __launch_bounds__(256) void agg_ln_l2_g3(
    const int2* __restrict__ ptrSE, const int* __restrict__ col,
    const float* __restrict__ asrc, const float* __restrict__ adst,
    const bf16* __restrict__ hb, const float* __restrict__ bias,
    const float* __restrict__ g, const float* __restrict__ be,
    const float* __restrict__ W3, const float* __restrict__ as3,
    const float* __restrict__ ad3,
    bf16* __restrict__ h3, float* __restrict__ asrc3, float* __restrict__ adst3,
    int N)
{
    constexpr int M = 64, LPD = 16, PF = 4, H = 4, DPBk = 16;
    __shared__ float Wl[640], s3[10], d3[10];
    int tid = threadIdx.x;
    for (int i = tid; i < 640; i += 256) Wl[i] = W3[i];
    if (tid < 10) { s3[tid] = as3[tid]; d3[tid] = ad3[tid]; }
    __syncthreads();
    int sub = tid >> 4;
    int j = tid & 15;
    int d = blockIdx.x * DPBk + sub;
    if (d >= N) return;
    int f0 = j * PF;
    int hd = f0 / 16;
    int2 se = ptrSE[d];
    int e = se.x, end = se.y;
    float adst_h = adst[d * H + hd];
    const unsigned short* hw = (const unsigned short*)hb;

    float ac0[PF], ac1[PF];
    float dn0, dn1 = 0.f;
    {
        float lg = asrc[d * H + hd] + adst_h;
        lg = lg > 0.f ? lg : 0.2f * lg;
        float w = __expf(lg);
        float v[PF];
        ldbfv<PF>(hw + (size_t)d * M + f0, v);
        #pragma unroll
        for (int p = 0; p < PF; ++p) { ac0[p] = w * v[p]; ac1[p] = 0.f; }
        dn0 = w;
    }
    for (; e + 4 <= end; e += 4) {
        int s0 = col[e], s1 = col[e + 1], s2 = col[e + 2], s3i = col[e + 3];
        float l0 = asrc[s0 * H + hd];
        float l1 = asrc[s1 * H + hd];
        float l2 = asrc[s2 * H + hd];
        float l3 = asrc[s3i * H + hd];
        float v0[PF], v1[PF], v2[PF], v3[PF];
        ldbfv<PF>(hw + (size_t)s0 * M + f0, v0);
        ldbfv<PF>(hw + (size_t)s1 * M + f0, v1);
        ldbfv<PF>(hw + (size_t)s2 * M + f0, v2);
        ldbfv<PF>(hw + (size_t)s3i * M + f0, v3);
        l0 += adst_h; l0 = l0 > 0.f ? l0 : 0.2f * l0; float w0 = __expf(l0);
        l1 += adst_h; l1 = l1 > 0.f ? l1 : 0.2f * l1; float w1 = __expf(l1);
        l2 += adst_h; l2 = l2 > 0.f ? l2 : 0.2f * l2; float w2 = __expf(l2);
        l3 += adst_h; l3 = l3 > 0.f ? l3 : 0.2f * l3; float w3 = __expf(l3);
        #pragma unroll
        for (int p = 0; p < PF; ++p) {
            ac0[p] += w0 * v0[p];
            ac1[p] += w1 * v1[p];
            ac0[p] += w2 * v2[p];
            ac1[p] += w3 * v3[p];
        }
        dn0 += w0 + w2; dn1 += w1 + w3;
    }
    for (; e < end; ++e) {
        int s = col[e];
        float lg = asrc[s * H + hd] + adst_h;
        lg = lg > 0.f ? lg : 0.2f * lg;
        float w = __expf(lg);
        float v[PF];
        ldbfv<PF>(hw + (size_t)s * M + f0, v);
        #pragma unroll
        for (int p = 0; p < PF; ++p) ac0[p] += w * v[p];
        dn0 += w;
    }

    float rden = 1.f / (dn0 + dn1 + 1e-16f);
    float o[PF];
    float sm1 = 0.f, sm2 = 0.f;
    #pragma unroll
    for (int p = 0; p < PF; ++p) {
        o[p] = (ac0[p] + ac1[p]) * rden + bias[f0 + p];
        sm1 += o[p];
        sm2 += o[p] * o[p];
    }
    #pragma unroll
    for (int off = 8; off >= 1; off >>= 1) {
        sm1 += __shfl_xor(sm1, off, 16);
        sm2 += __shfl_xor(sm2, off, 16);
    }
    float mu = sm1 * (1.f / M);
    float var = sm2 * (1.f / M) - mu * mu;
    float inv = rsqrtf(var + 1e-5f);
    float y[PF];
    #pragma unroll
    for (int p = 0; p < PF; ++p) {
        float t = (o[p] - mu) * inv * g[f0 + p] + be[f0 + p];
        y[p] = t > 0.f ? t : expm1f(t);
    }
    // fused gemm3: partials over this lane's 4 features, butterfly over 16 lanes
    float pj[10];
    #pragma unroll
    for (int jj = 0; jj < 10; ++jj)
        pj[jj] = y[0] * Wl[(f0 + 0) * 10 + jj] + y[1] * Wl[(f0 + 1) * 10 + jj]
               + y[2] * Wl[(f0 + 2) * 10 + jj] + y[3] * Wl[(f0 + 3) * 10 + jj];
    #pragma unroll
    for (int off = 8; off >= 1; off >>= 1)
        #pragma unroll
        for (int jj = 0; jj < 10; ++jj)
            pj[jj] += __shfl_xor(pj[jj], off, 16);
    if (j == 0) {
        unsigned short* hr = (unsigned short*)h3 + (size_t)d * 16;
        #pragma unroll
        for (int jj = 0; jj < 10; jj += 2) {
            unsigned u = (unsigned)f2bu(pj[jj]) | ((unsigned)f2bu(pj[jj + 1]) << 16);
            *reinterpret_cast<unsigned*>(hr + jj) = u;
        }
        float a1 = 0.f, a2 = 0.f;
        #pragma unroll
        for (int jj = 0; jj < 10; ++jj) {
            a1 += pj[jj] * s3[jj];
            a2 += pj[jj] * d3[jj];
        }
        asrc3[d] = a1;
        adst3[d] = a2;
    }
}

// --- layer-3 agg + bias + log_softmax fused: 16-lane subgroup per dst -------
__global__ __launch_bounds__(256) void agg_l3_final(
    const int2* __restrict__ ptrSE, const int* __restrict__ col,
    const float* __restrict__ asrc, const float* __restrict__ adst,
    const bf16* __restrict__ h, const float* __restrict__ b3,
    float* __restrict__ out, int N)
{
    int tid = threadIdx.x;
    int sub16 = tid >> 4;
    int j = tid & 15;
    int d = blockIdx.x * 16 + sub16;
    if (d >= N) return;
    const unsigned short* hu = (const unsigned short*)h;
    int2 se = ptrSE[d];
    int e = se.x, end = se.y;
    float adst_d = adst[d];
    float lg = asrc[d] + adst_d;
    lg = lg > 0.f ? lg : 0.2f * lg;
    float w = __expf(lg);
    bool act = j < 10;
    float a0 = act ? w * bu2f(hu[(size_t)d * 16 + j]) : 0.f;
    float a1 = 0.f, a2 = 0.f, a3 = 0.f;
    float d0 = w, d1 = 0.f, d2 = 0.f, d3 = 0.f;
    for (; e + 4 <= end; e += 4) {
        int s0 = col[e + 0], s1 = col[e + 1], s2 = col[e + 2], s3 = col[e + 3];
        float l0 = asrc[s0], l1 = asrc[s1], l2 = asrc[s2], l3 = asrc[s3];
        float v0 = act ? bu2f(hu[(size_t)s0 * 16 + j]) : 0.f;
        float v1 = act ? bu2f(hu[(size_t)s1 * 16 + j]) : 0.f;
        float v2 = act ? bu2f(hu[(size_t)s2 * 16 + j]) : 0.f;
        float v3 = act ? bu2f(hu[(size_t)s3 * 16 + j]) : 0.f;
        l0 += adst_d; l0 = l0 > 0.f ? l0 : 0.2f * l0; float w0 = __expf(l0);
        l1 += adst_d; l1 = l1 > 0.f ? l1 : 0.2f * l1; float w1 = __expf(l1);
        l2 += adst_d; l2 = l2 > 0.f ? l2 : 0.2f * l2; float w2 = __expf(l2);
        l3 += adst_d; l3 = l3 > 0.f ? l3 : 0.2f * l3; float w3 = __expf(l3);
        a0 += w0 * v0; a1 += w1 * v1; a2 += w2 * v2; a3 += w3 * v3;
        d0 += w0; d1 += w1; d2 += w2; d3 += w3;
    }
    for (; e < end; ++e) {
        int s = col[e];
        float l = asrc[s] + adst_d;
        l = l > 0.f ? l : 0.2f * l;
        float ww = __expf(l);
        if (act) a0 += ww * bu2f(hu[(size_t)s * 16 + j]);
        d0 += ww;
    }
    float den = d0 + d1 + d2 + d3;
    float v = (a0 + a1 + a2 + a3) / (den + 1e-16f);
    float lv = act ? v + b3[j] : -1e30f;
    float mx = lv;
    #pragma unroll
    for (int off = 1; off < 16; off <<= 1) mx = fmaxf(mx, __shfl_xor(mx, off, 16));
    float ev = act ? __expf(lv - mx) : 0.f;
    float se2 = ev;
    #pragma unroll
    for (int off = 1; off < 16; off <<= 1) se2 += __shfl_xor(se2, off, 16);
    float ls = mx + logf(se2);
    if (act) out[(size_t)d * 10 + j] = lv - ls;
}

static inline int cdiv(long a, long b) { return (int)((a + b - 1) / b); }

extern "C" void kernel_launch(void* const* d_in, const int* in_sizes, int n_in,
                              void* d_out, int out_size, void* d_ws, size_t ws_size,
                              hipStream_t stream)
{
    const float* x   = (const float*)d_in[0];
    const int*   ei  = (const int*)d_in[1];
    const float* W1  = (const float*)d_in[2];
    const float* as1 = (const float*)d_in[3];
    const float* ad1 = (const float*)d_in[4];
    const float* b1  = (const float*)d_in[5];
    const float* g1  = (const float*)d_in[6];
    const float* be1 = (const float*)d_in[7];
    const float* W2  = (const float*)d_in[8];
    const float* as2 = (const float*)d_in[9];
    const float* ad2 = (const float*)d_in[10];
    const float* b2  = (const float*)d_in[11];
    const float* g2  = (const float*)d_in[12];
    const float* be2 = (const float*)d_in[13];
    const float* W3  = (const float*)d_in[14];
    const float* as3 = (const float*)d_in[15];
    const float* ad3 = (const float*)d_in[16];
    const float* b3  = (const float*)d_in[17];

    const int N = in_sizes[0] / 128;
    const int E = in_sizes[1] / 2;

    const int DPB  = cdiv(N, 256);
    const int NBLK = cdiv(E, CSR_CH);

    bf16*     hb    = (bf16*)d_ws;                      // N*128 bf16 (gather table)
    bf16*     aggb  = hb + (size_t)N * 128;             // N*128 bf16 (LN out L1 / h3 L3)
    float*    asrc  = (float*)(aggb + (size_t)N * 128); // N*8
    float*    adst  = asrc + (size_t)N * 8;             // N*8
    float*    asrc3 = adst + (size_t)N * 8;             // N
    float*    adst3 = asrc3 + N;                        // N
    unsigned* pairs = (unsigned*)(adst3 + N);           // 256*REG u32
    int*      col   = (int*)(pairs + 256 * CSR_REG);    // 256*REG
    int2*     ptrSE = (int2*)(col + 256 * CSR_REG);     // N
    int*      histM = (int*)(ptrSE + N);                // NBLK*256
    int*      offT  = histM + (size_t)NBLK * 256;       // 256*NBLK
    int*      btot  = offT + (size_t)NBLK * 256;        // 256
    bf16*     h3b   = aggb;                             // N*16 bf16 (layer 3 logits)

    const int NG1 = cdiv(N, 64);

    // layer-1 GEMM (+alpha) fused with csr_hist blocks
    gemm_mfma<float, 8><<<NG1 + NBLK, 256, 0, stream>>>(
        x, W1, as1, ad1, hb, asrc, adst, N, NG1, ei, E, DPB, histM);
    csr_colscan<<<256, 256, 0, stream>>>(histM, NBLK, offT, btot);
    csr_pair_scatter<<<NBLK, 256, 0, stream>>>(ei, E, DPB, offT, NBLK, pairs);
    csr_fine<<<256, 256, 0, stream>>>(pairs, btot, DPB, N, ptrSE, col);

    // layer 1 aggregation -> LN -> ELU (bf16 out in aggb)
    agg_ln_kernel<128, 16><<<cdiv(N, 16), 256, 0, stream>>>(
        ptrSE, col, asrc, adst, hb, b1, g1, be1, aggb, N);

    // layer 2 GEMM (+alpha), no hist blocks
    const int NG2 = cdiv(N, 64);
    gemm_mfma<bf16, 4><<<NG2, 256, 0, stream>>>(
        aggb, W2, as2, ad2, hb, asrc, adst, N, NG2, nullptr, 0, 1, nullptr);

    // layer 2 aggregation -> LN -> ELU -> fused gemm3 + alpha3 (h3 into aggb)
    agg_ln_l2_g3<<<cdiv(N, 16), 256, 0, stream>>>(
        ptrSE, col, asrc, adst, hb, b2, g2, be2, W3, as3, ad3,
        h3b, asrc3, adst3, N);

    // layer 3 aggregation + bias + log_softmax -> d_out
    agg_l3_final<<<cdiv(N, 16), 256, 0, stream>>>(
        ptrSE, col, asrc3, adst3, h3b, b3, (float*)d_out, N);
}